// Round 2
// baseline (3359.142 us; speedup 1.0000x reference)
//
#include <hip/hip_runtime.h>
#include <cstdint>

#define D 128

typedef __attribute__((ext_vector_type(8))) short short8;
typedef __attribute__((ext_vector_type(4))) float f32x4;

__device__ inline ushort f2bf(float f) {
    uint u = __float_as_uint(f);
    uint r = (u + 0x7fffu + ((u >> 16) & 1u)) >> 16;
    return (ushort)r;
}
__device__ inline float bf2f(ushort u) { return __uint_as_float(((uint)u) << 16); }

// ---------------------------------------------------------------- degree / CSR build

__global__ void k_count(const int* __restrict__ src, const int* __restrict__ dst,
                        int E, float* __restrict__ degs, float* __restrict__ degd) {
    int i = blockIdx.x * blockDim.x + threadIdx.x;
    if (i < E) {
        atomicAdd(&degs[src[i]], 1.0f);
        atomicAdd(&degd[dst[i]], 1.0f);
    }
}

__global__ void k_rsqrt(float* __restrict__ p, int n) {
    int i = blockIdx.x * blockDim.x + threadIdx.x;
    if (i < n) {
        float d = p[i];
        p[i] = d > 0.0f ? rsqrtf(d) : 0.0f;
    }
}

__global__ void k_scan1(const float* __restrict__ cnt, int* __restrict__ off,
                        int* __restrict__ bsum, int n) {
    __shared__ int s[256];
    int t = threadIdx.x, i = blockIdx.x * 256 + t;
    int v = (i < n) ? (int)cnt[i] : 0;
    int acc = v;
    s[t] = acc; __syncthreads();
    for (int d = 1; d < 256; d <<= 1) {
        int add = (t >= d) ? s[t - d] : 0;
        __syncthreads();
        acc += add; s[t] = acc; __syncthreads();
    }
    if (i < n) off[i] = acc - v;
    if (t == 255) bsum[blockIdx.x] = acc;
}

__global__ __launch_bounds__(1024) void k_scan2(int* __restrict__ bsum, int nb) {
    __shared__ int s[1024];
    int t = threadIdx.x;
    int i0 = t * 3;
    int v0 = (i0     < nb) ? bsum[i0]     : 0;
    int v1 = (i0 + 1 < nb) ? bsum[i0 + 1] : 0;
    int v2 = (i0 + 2 < nb) ? bsum[i0 + 2] : 0;
    int tot = v0 + v1 + v2;
    int acc = tot;
    s[t] = acc; __syncthreads();
    for (int d = 1; d < 1024; d <<= 1) {
        int add = (t >= d) ? s[t - d] : 0;
        __syncthreads();
        acc += add; s[t] = acc; __syncthreads();
    }
    int base = acc - tot;
    if (i0     < nb) bsum[i0]     = base;
    if (i0 + 1 < nb) bsum[i0 + 1] = base + v0;
    if (i0 + 2 < nb) bsum[i0 + 2] = base + v0 + v1;
}

__global__ void k_scan3(int* __restrict__ off, const int* __restrict__ bsum, int n) {
    int i = blockIdx.x * 256 + threadIdx.x;
    if (i < n) off[i] += bsum[blockIdx.x];
}

__global__ void k_fill(const int* __restrict__ src, const int* __restrict__ dst,
                       int E, int* __restrict__ offs, int* __restrict__ sorted) {
    int e = blockIdx.x * blockDim.x + threadIdx.x;
    if (e < E) {
        int pos = atomicAdd(&offs[dst[e]], 1);
        sorted[pos] = src[e];
    }
}

// W[18][128k][128n] fp32 -> Wf fragment-major bf16:
// Wf[r][c][kbi][lane][e]  (c=col-tile 0..7, kbi=k-block 0..3, lane=lm+16*lg, e=0..7)
//   holds W[k = kbi*32 + lg*8 + e][ncol = c*16 + lm]
// so the GEMM's ds_read_b128 at (frag*64 + lane)*16B is lane-contiguous -> conflict-free.
__global__ void k_prepw(const float* __restrict__ W, ushort* __restrict__ Wf) {
    int i = blockIdx.x * 256 + threadIdx.x;
    if (i < 18 * 16384) {
        int r = i >> 14, j = i & 16383;
        int e = j & 7, lane = (j >> 3) & 63, kbi = (j >> 9) & 3, c = j >> 11;
        int lm = lane & 15, lg = lane >> 4;
        int k = kbi * 32 + lg * 8 + e, ncol = c * 16 + lm;
        Wf[i] = f2bf(W[(r << 14) + (k << 7) + ncol]);
    }
}

// ---------------------------------------------------------------- fused gather + MFMA GEMM + BN stats

__device__ inline float4 loadx(const float* x, size_t idx) { return *(const float4*)(x + idx); }
__device__ inline float4 loadx(const ushort* x, size_t idx) {
    ushort4 u = *(const ushort4*)(x + idx);
    float4 v;
    v.x = bf2f(u.x); v.y = bf2f(u.y); v.z = bf2f(u.z); v.w = bf2f(u.w);
    return v;
}

// Block: 256 thr = 4 waves, 64 dst rows. Phase 1: CSR gather of this block's
// rows straight into LDS A-tile (bf16, nd pre-applied) -- no mbuf round trip.
// Phase 2: each wave does one 16-row m-fragment x full 128 cols via MFMA,
// BN stats accumulated in registers, one LDS reduce + global atomics.
template <typename XT>
__global__ __launch_bounds__(256) void k_fused(
    const XT* __restrict__ x, const float* __restrict__ ns,
    const float* __restrict__ nd,
    const int* __restrict__ OFFS, int gdbase,
    const int* __restrict__ sorted,
    const ushort* __restrict__ Wf,
    int n, float* __restrict__ outp, float* __restrict__ stats) {
    __shared__ ushort Wl[16384];      // 32 KB fragment-major W
    __shared__ ushort Al[64 * 136];   // padded row-major A tile (writes ~conflict-free)
    __shared__ float Sl[256];
    int t = threadIdx.x;
    Sl[t] = 0.0f;

    // stage W: linear 32KB copy (loads issue now, complete during gather)
    #pragma unroll
    for (int i = 0; i < 8; ++i) {
        int ci = t + 256 * i;
        *(short8*)&Wl[ci * 8] = *(const short8*)&Wf[ci * 8];
    }

    int r0 = blockIdx.x * 64;
    int quad = t & 31, rgrp = t >> 5;
    int c4 = quad * 4;
    for (int it = 0; it < 8; ++it) {
        int rl = rgrp + 8 * it;          // 0..63
        int row = r0 + rl;
        float4 acc = {0.f, 0.f, 0.f, 0.f};
        float scale = 0.f;
        if (row < n) {
            int gd = gdbase + row;
            int beg = (gd == 0) ? 0 : OFFS[gd - 1];
            int end = OFFS[gd];
            for (int j = beg; j < end; ++j) {
                int s = sorted[j];
                float w = ns[s];
                float4 v = loadx(x, ((size_t)s << 7) + c4);
                acc.x += v.x * w; acc.y += v.y * w; acc.z += v.z * w; acc.w += v.w * w;
            }
            scale = nd[row];
        }
        ushort4 o;
        o.x = f2bf(acc.x * scale); o.y = f2bf(acc.y * scale);
        o.z = f2bf(acc.z * scale); o.w = f2bf(acc.w * scale);
        *(ushort4*)&Al[rl * 136 + c4] = o;   // rows >= n written as zeros
    }
    __syncthreads();

    int w = t >> 6, lane = t & 63, lm = lane & 15, lg = lane >> 4;
    float rs1[8] = {0.f, 0.f, 0.f, 0.f, 0.f, 0.f, 0.f, 0.f};
    float rs2[8] = {0.f, 0.f, 0.f, 0.f, 0.f, 0.f, 0.f, 0.f};
    int R = r0 + w * 16;

    if (R < n) {
        f32x4 acc[8] = {};
        int abase = (w * 16 + lm) * 136 + lg * 8;
        #pragma unroll
        for (int kbi = 0; kbi < 4; ++kbi) {
            short8 a = *(short8*)&Al[abase + kbi * 32];
            #pragma unroll
            for (int c = 0; c < 8; ++c) {
                short8 b = *(short8*)&Wl[((c * 4 + kbi) * 64 + lane) * 8];
                acc[c] = __builtin_amdgcn_mfma_f32_16x16x32_bf16(a, b, acc[c], 0, 0, 0);
            }
        }
        int rowb = R + lg * 4;
        #pragma unroll
        for (int c = 0; c < 8; ++c) {
            f32x4 v = acc[c];
            rs1[c] += v[0] + v[1] + v[2] + v[3];
            rs2[c] += v[0] * v[0] + v[1] * v[1] + v[2] * v[2] + v[3] * v[3];
            #pragma unroll
            for (int i2 = 0; i2 < 4; ++i2) {
                int row = rowb + i2;
                if (row < n)
                    outp[((size_t)row << 7) + c * 16 + lm] = v[i2];
            }
        }
    }

    // stats: lane's values belong to channel c*16+lm; reduce over lg via shfl
    #pragma unroll
    for (int c = 0; c < 8; ++c) {
        float s1 = rs1[c], s2 = rs2[c];
        s1 += __shfl_xor(s1, 16); s1 += __shfl_xor(s1, 32);
        s2 += __shfl_xor(s2, 16); s2 += __shfl_xor(s2, 32);
        if (lg == 0) {
            atomicAdd(&Sl[c * 16 + lm], s1);
            atomicAdd(&Sl[128 + c * 16 + lm], s2);
        }
    }
    __syncthreads();
    atomicAdd(&stats[t], Sl[t]);
}

// ---------------------------------------------------------------- BN normalize

// fp32 dst. mode 1: dst += v; mode 2: dst = v + resid
__global__ void k_norm(const float4* __restrict__ out4, const float* __restrict__ stats,
                       const float* __restrict__ gamma, const float* __restrict__ beta,
                       float inv_n, int total4, float4* __restrict__ dst4,
                       const float4* __restrict__ resid4, int mode) {
    __shared__ float sc[128], sh[128];
    int t = threadIdx.x;
    if (t < 128) {
        float mu = stats[t] * inv_n;
        float var = stats[128 + t] * inv_n - mu * mu;
        float s = gamma[t] * rsqrtf(var + 1e-5f);
        sc[t] = s;
        sh[t] = beta[t] - mu * s;
    }
    __syncthreads();
    for (int i = blockIdx.x * blockDim.x + t; i < total4; i += gridDim.x * blockDim.x) {
        int c4 = (i & 31) * 4;
        float4 v = out4[i];
        float4 r;
        r.x = v.x * sc[c4 + 0] + sh[c4 + 0];
        r.y = v.y * sc[c4 + 1] + sh[c4 + 1];
        r.z = v.z * sc[c4 + 2] + sh[c4 + 2];
        r.w = v.w * sc[c4 + 3] + sh[c4 + 3];
        if (mode == 1) {
            float4 d = dst4[i];
            r.x += d.x; r.y += d.y; r.z += d.z; r.w += d.w;
        } else if (mode == 2) {
            float4 d = resid4[i];
            r.x += d.x; r.y += d.y; r.z += d.z; r.w += d.w;
        }
        dst4[i] = r;
    }
}

// bf16 dst. mode 0: dst = v; mode 1: dst += v
__global__ void k_norm_bf(const float4* __restrict__ out4, const float* __restrict__ stats,
                          const float* __restrict__ gamma, const float* __restrict__ beta,
                          float inv_n, int total4, ushort* __restrict__ dst, int mode) {
    __shared__ float sc[128], sh[128];
    int t = threadIdx.x;
    if (t < 128) {
        float mu = stats[t] * inv_n;
        float var = stats[128 + t] * inv_n - mu * mu;
        float s = gamma[t] * rsqrtf(var + 1e-5f);
        sc[t] = s;
        sh[t] = beta[t] - mu * s;
    }
    __syncthreads();
    for (int i = blockIdx.x * blockDim.x + t; i < total4; i += gridDim.x * blockDim.x) {
        int c4 = (i & 31) * 4;
        float4 v = out4[i];
        float4 r;
        r.x = v.x * sc[c4 + 0] + sh[c4 + 0];
        r.y = v.y * sc[c4 + 1] + sh[c4 + 1];
        r.z = v.z * sc[c4 + 2] + sh[c4 + 2];
        r.w = v.w * sc[c4 + 3] + sh[c4 + 3];
        if (mode == 1) {
            ushort4 d = *(const ushort4*)(dst + (size_t)i * 4);
            r.x += bf2f(d.x); r.y += bf2f(d.y); r.z += bf2f(d.z); r.w += bf2f(d.w);
        }
        ushort4 o;
        o.x = f2bf(r.x); o.y = f2bf(r.y); o.z = f2bf(r.z); o.w = f2bf(r.w);
        *(ushort4*)(dst + (size_t)i * 4) = o;
    }
}

// ---------------------------------------------------------------- launch

extern "C" void kernel_launch(void* const* d_in, const int* in_sizes, int n_in,
                              void* d_out, int out_size, void* d_ws, size_t ws_size,
                              hipStream_t stream) {
    static const int NT[3]   = {100000, 150000, 2000};
    static const int RE[9]   = {300000, 300000, 100000, 100000, 150000, 150000, 100000, 150000, 2000};
    static const int RSRC[9] = {0, 1, 0, 2, 1, 2, 0, 1, 2};
    static const int RDST[9] = {1, 0, 2, 0, 2, 1, 0, 1, 2};
    const int TOT_N = 756000;
    const int NB = (TOT_N + 255) / 256;

    const float* feat_in[3] = {(const float*)d_in[0], (const float*)d_in[1], (const float*)d_in[2]};
    const float* W     = (const float*)d_in[3];
    const float* gamma = (const float*)d_in[5];
    const float* beta  = (const float*)d_in[6];
    float* ws  = (float*)d_ws;
    float* out = (float*)d_out;

    int ns_base[9], nd_base[9];
    {
        int s = 0, d = 0;
        for (int r = 0; r < 9; ++r) {
            ns_base[r] = s; s += NT[RSRC[r]];
            nd_base[r] = d; d += NT[RDST[r]];
        }
    }

    // workspace layout (float units; bf16 buffers use half-count)
    const size_t H_A    = 0;                        // 100000*128 bf16
    const size_t H_B    = H_A + 6400000;            // 150000*128 bf16
    const size_t H_G    = H_B + 9600000;            // 2000*128 bf16
    const size_t MBUF   = H_G + 128000;             // (unused hole)
    const size_t OUT    = MBUF + 9600000;           // 150000*128 fp32
    const size_t WT     = OUT + 19200000;           // 18*128*128 bf16
    const size_t STATS  = WT + 147456;              // 18*256 fp32
    const size_t NS     = STATS + 4608;             // 756000
    const size_t ND     = NS + 756000;              // 756000
    const size_t OFFS   = ND + 756000;              // 756000 ints
    const size_t SORTED = OFFS + 756000;            // 1352000 ints
    const size_t BSUM   = SORTED + 1352000;         // scan blocks

    ushort* h_feat[3] = {(ushort*)(ws + H_A), (ushort*)(ws + H_B), (ushort*)(ws + H_G)};
    float* out_feat[3] = {out, out + 12800000, out + 32000000};
    float*  obuf   = ws + OUT;
    ushort* wt     = (ushort*)(ws + WT);
    float*  stats0 = ws + STATS;
    float*  ns_blk = ws + NS;
    float*  nd_blk = ws + ND;
    int*    offs   = (int*)(ws + OFFS);
    int*    sorted = (int*)(ws + SORTED);
    int*    bsum   = (int*)(ws + BSUM);

    // zero stats + degree counters (contiguous)
    hipMemsetAsync(ws + STATS, 0, (4608 + 2 * 756000) * sizeof(float), stream);

    for (int r = 0; r < 9; ++r) {
        const int* src = (const int*)d_in[7 + 2 * r];
        const int* dst = (const int*)d_in[8 + 2 * r];
        k_count<<<(RE[r] + 255) / 256, 256, 0, stream>>>(
            src, dst, RE[r], ns_blk + ns_base[r], nd_blk + nd_base[r]);
    }
    k_scan1<<<NB, 256, 0, stream>>>(nd_blk, offs, bsum, TOT_N);
    k_scan2<<<1, 1024, 0, stream>>>(bsum, NB);
    k_scan3<<<NB, 256, 0, stream>>>(offs, bsum, TOT_N);
    for (int r = 0; r < 9; ++r) {
        const int* src = (const int*)d_in[7 + 2 * r];
        const int* dst = (const int*)d_in[8 + 2 * r];
        k_fill<<<(RE[r] + 255) / 256, 256, 0, stream>>>(
            src, dst, RE[r], offs + nd_base[r], sorted);
    }
    k_rsqrt<<<(2 * TOT_N + 255) / 256, 256, 0, stream>>>(ns_blk, 2 * TOT_N);
    k_prepw<<<(18 * 16384 + 255) / 256, 256, 0, stream>>>(W, wt);

    for (int l = 0; l < 2; ++l) {
        bool touched[3] = {false, false, false};
        for (int r = 0; r < 9; ++r) {
            int st = RSRC[r], dt = RDST[r];
            int n_dst = NT[dt];

            float* stats = stats0 + (size_t)(l * 9 + r) * 256;
            const ushort* wfr = wt + (size_t)(l * 9 + r) * 16384;
            int nblk = (n_dst + 63) / 64;

            if (l == 0)
                k_fused<float><<<nblk, 256, 0, stream>>>(
                    feat_in[st], ns_blk + ns_base[r], nd_blk + nd_base[r],
                    offs, nd_base[r], sorted, wfr, n_dst, obuf, stats);
            else
                k_fused<ushort><<<nblk, 256, 0, stream>>>(
                    h_feat[st], ns_blk + ns_base[r], nd_blk + nd_base[r],
                    offs, nd_base[r], sorted, wfr, n_dst, obuf, stats);

            int total4 = n_dst * 32;
            int ngrid = (total4 + 255) / 256;
            if (ngrid > 2048) ngrid = 2048;
            const float* g = gamma + (size_t)(l * 9 + r) * D;
            const float* b = beta  + (size_t)(l * 9 + r) * D;
            if (l == 0) {
                int mode = touched[dt] ? 1 : 0;
                k_norm_bf<<<ngrid, 256, 0, stream>>>(
                    (const float4*)obuf, stats, g, b, 1.0f / (float)n_dst,
                    total4, h_feat[dt], mode);
            } else {
                int mode = touched[dt] ? 1 : 2;
                k_norm<<<ngrid, 256, 0, stream>>>(
                    (const float4*)obuf, stats, g, b, 1.0f / (float)n_dst,
                    total4, (float4*)out_feat[dt], (const float4*)feat_in[dt], mode);
            }
            touched[dt] = true;
        }
    }
}

// Round 3
// 2256.829 us; speedup vs baseline: 1.4884x; 1.4884x over previous
//
#include <hip/hip_runtime.h>
#include <cstdint>

#define D 128

typedef __attribute__((ext_vector_type(8))) short short8;
typedef __attribute__((ext_vector_type(4))) float f32x4;

__device__ inline ushort f2bf(float f) {
    uint u = __float_as_uint(f);
    uint r = (u + 0x7fffu + ((u >> 16) & 1u)) >> 16;
    return (ushort)r;
}
__device__ inline float bf2f(ushort u) { return __uint_as_float(((uint)u) << 16); }

// ---------------------------------------------------------------- degree / CSR build

__global__ void k_count(const int* __restrict__ src, const int* __restrict__ dst,
                        int E, float* __restrict__ degs, float* __restrict__ degd) {
    int i = blockIdx.x * blockDim.x + threadIdx.x;
    if (i < E) {
        atomicAdd(&degs[src[i]], 1.0f);
        atomicAdd(&degd[dst[i]], 1.0f);
    }
}

__global__ void k_rsqrt(float* __restrict__ p, int n) {
    int i = blockIdx.x * blockDim.x + threadIdx.x;
    if (i < n) {
        float d = p[i];
        p[i] = d > 0.0f ? rsqrtf(d) : 0.0f;
    }
}

__global__ void k_scan1(const float* __restrict__ cnt, int* __restrict__ off,
                        int* __restrict__ bsum, int n) {
    __shared__ int s[256];
    int t = threadIdx.x, i = blockIdx.x * 256 + t;
    int v = (i < n) ? (int)cnt[i] : 0;
    int acc = v;
    s[t] = acc; __syncthreads();
    for (int d = 1; d < 256; d <<= 1) {
        int add = (t >= d) ? s[t - d] : 0;
        __syncthreads();
        acc += add; s[t] = acc; __syncthreads();
    }
    if (i < n) off[i] = acc - v;
    if (t == 255) bsum[blockIdx.x] = acc;
}

__global__ __launch_bounds__(1024) void k_scan2(int* __restrict__ bsum, int nb) {
    __shared__ int s[1024];
    int t = threadIdx.x;
    int i0 = t * 3;
    int v0 = (i0     < nb) ? bsum[i0]     : 0;
    int v1 = (i0 + 1 < nb) ? bsum[i0 + 1] : 0;
    int v2 = (i0 + 2 < nb) ? bsum[i0 + 2] : 0;
    int tot = v0 + v1 + v2;
    int acc = tot;
    s[t] = acc; __syncthreads();
    for (int d = 1; d < 1024; d <<= 1) {
        int add = (t >= d) ? s[t - d] : 0;
        __syncthreads();
        acc += add; s[t] = acc; __syncthreads();
    }
    int base = acc - tot;
    if (i0     < nb) bsum[i0]     = base;
    if (i0 + 1 < nb) bsum[i0 + 1] = base + v0;
    if (i0 + 2 < nb) bsum[i0 + 2] = base + v0 + v1;
}

__global__ void k_scan3(int* __restrict__ off, const int* __restrict__ bsum, int n) {
    int i = blockIdx.x * 256 + threadIdx.x;
    if (i < n) off[i] += bsum[blockIdx.x];
}

__global__ void k_fill(const int* __restrict__ src, const int* __restrict__ dst,
                       int E, int* __restrict__ offs, int* __restrict__ sorted) {
    int e = blockIdx.x * blockDim.x + threadIdx.x;
    if (e < E) {
        int pos = atomicAdd(&offs[dst[e]], 1);
        sorted[pos] = src[e];
    }
}

// W[18][128k][128n] fp32 -> Wf fragment-major bf16:
// Wf[r][c][kbi][lane][e]  (c=col-tile 0..7, kbi=k-block 0..3, lane=lm+16*lg, e=0..7)
//   holds W[k = kbi*32 + lg*8 + e][ncol = c*16 + lm]
__global__ void k_prepw(const float* __restrict__ W, ushort* __restrict__ Wf) {
    int i = blockIdx.x * 256 + threadIdx.x;
    if (i < 18 * 16384) {
        int r = i >> 14, j = i & 16383;
        int e = j & 7, lane = (j >> 3) & 63, kbi = (j >> 9) & 3, c = j >> 11;
        int lm = lane & 15, lg = lane >> 4;
        int k = kbi * 32 + lg * 8 + e, ncol = c * 16 + lm;
        Wf[i] = f2bf(W[(r << 14) + (k << 7) + ncol]);
    }
}

// ---------------------------------------------------------------- gather helpers

__device__ inline float4 loadx(const float* x, size_t idx) { return *(const float4*)(x + idx); }
__device__ inline float4 loadx(const ushort* x, size_t idx) {
    ushort4 u = *(const ushort4*)(x + idx);
    float4 v;
    v.x = bf2f(u.x); v.y = bf2f(u.y); v.z = bf2f(u.z); v.w = bf2f(u.w);
    return v;
}

// separate gather (small-n_dst path): 32 threads per row, one row per thread-group
template <typename XT>
__global__ void k_gather(const XT* __restrict__ x, const float* __restrict__ ns,
                         const float* __restrict__ nd,
                         const int* __restrict__ OFFS, int gdbase,
                         const int* __restrict__ sorted, int n_dst,
                         ushort* __restrict__ m) {
    int gid = blockIdx.x * blockDim.x + threadIdx.x;
    int row = gid >> 5;
    if (row >= n_dst) return;
    int c4 = (gid & 31) * 4;
    int gd = gdbase + row;
    int beg = (gd == 0) ? 0 : OFFS[gd - 1];
    int end = OFFS[gd];
    float4 acc = {0.f, 0.f, 0.f, 0.f};
    for (int j = beg; j < end; ++j) {
        int s = sorted[j];
        float w = ns[s];
        float4 v = loadx(x, ((size_t)s << 7) + c4);
        acc.x += v.x * w; acc.y += v.y * w; acc.z += v.z * w; acc.w += v.w * w;
    }
    float sc = nd[row];
    ushort4 o;
    o.x = f2bf(acc.x * sc); o.y = f2bf(acc.y * sc);
    o.z = f2bf(acc.z * sc); o.w = f2bf(acc.w * sc);
    *(ushort4*)(m + ((size_t)row << 7) + c4) = o;
}

// separate GEMM (small-n_dst path): 4 waves, each owns an independent 32-row tile
__global__ __launch_bounds__(256) void k_gemm_mfma(
    const ushort* __restrict__ mb, const ushort* __restrict__ Wf,
    int n, float* __restrict__ outp, float* __restrict__ stats) {
    __shared__ ushort Wl[16384];
    __shared__ float Sl[256];
    int t = threadIdx.x;
    int w = t >> 6, lane = t & 63, lm = lane & 15, lg = lane >> 4;
    Sl[t] = 0.0f;

    #pragma unroll
    for (int i = 0; i < 8; ++i) {
        int ci = t + 256 * i;
        *(short8*)&Wl[ci * 8] = *(const short8*)&Wf[ci * 8];
    }
    __syncthreads();

    int R = (blockIdx.x * 4 + w) * 32;
    float rs1[8] = {0.f, 0.f, 0.f, 0.f, 0.f, 0.f, 0.f, 0.f};
    float rs2[8] = {0.f, 0.f, 0.f, 0.f, 0.f, 0.f, 0.f, 0.f};

    if (R < n) {
        f32x4 acc[2][8] = {};
        int r0 = R + lm, r1 = R + 16 + lm;
        const ushort* a0p = mb + (((size_t)r0) << 7) + lg * 8;
        const ushort* a1p = mb + (((size_t)r1) << 7) + lg * 8;
        bool v0 = r0 < n, v1 = r1 < n;
        #pragma unroll
        for (int kbi = 0; kbi < 4; ++kbi) {
            short8 a0 = {}, a1 = {};
            if (v0) a0 = *(const short8*)(a0p + kbi * 32);
            if (v1) a1 = *(const short8*)(a1p + kbi * 32);
            #pragma unroll
            for (int c = 0; c < 8; ++c) {
                short8 b = *(short8*)&Wl[((c * 4 + kbi) * 64 + lane) * 8];
                acc[0][c] = __builtin_amdgcn_mfma_f32_16x16x32_bf16(a0, b, acc[0][c], 0, 0, 0);
                acc[1][c] = __builtin_amdgcn_mfma_f32_16x16x32_bf16(a1, b, acc[1][c], 0, 0, 0);
            }
        }
        #pragma unroll
        for (int m = 0; m < 2; ++m) {
            int rowb = R + m * 16 + lg * 4;
            #pragma unroll
            for (int c = 0; c < 8; ++c) {
                f32x4 v = acc[m][c];
                rs1[c] += v[0] + v[1] + v[2] + v[3];
                rs2[c] += v[0] * v[0] + v[1] * v[1] + v[2] * v[2] + v[3] * v[3];
                #pragma unroll
                for (int i2 = 0; i2 < 4; ++i2) {
                    int row = rowb + i2;
                    if (row < n)
                        outp[((size_t)row << 7) + c * 16 + lm] = v[i2];
                }
            }
        }
    }

    #pragma unroll
    for (int c = 0; c < 8; ++c) {
        float s1 = rs1[c], s2 = rs2[c];
        s1 += __shfl_xor(s1, 16); s1 += __shfl_xor(s1, 32);
        s2 += __shfl_xor(s2, 16); s2 += __shfl_xor(s2, 32);
        if (lg == 0) {
            atomicAdd(&Sl[c * 16 + lm], s1);
            atomicAdd(&Sl[128 + c * 16 + lm], s2);
        }
    }
    __syncthreads();
    atomicAdd(&stats[t], Sl[t]);
}

// ---------------------------------------------------------------- fused gather + MFMA GEMM (big-n_dst path)

template <typename XT>
__global__ __launch_bounds__(256) void k_fused(
    const XT* __restrict__ x, const float* __restrict__ ns,
    const float* __restrict__ nd,
    const int* __restrict__ OFFS, int gdbase,
    const int* __restrict__ sorted,
    const ushort* __restrict__ Wf,
    int n, float* __restrict__ outp, float* __restrict__ stats) {
    __shared__ ushort Wl[16384];      // 32 KB fragment-major W
    __shared__ ushort Al[64 * 136];   // padded row-major A tile
    __shared__ float Sl[256];
    int t = threadIdx.x;
    Sl[t] = 0.0f;

    // stage W: linear 32KB copy (loads issue now, complete during gather)
    #pragma unroll
    for (int i = 0; i < 8; ++i) {
        int ci = t + 256 * i;
        *(short8*)&Wl[ci * 8] = *(const short8*)&Wf[ci * 8];
    }

    int r0 = blockIdx.x * 64;
    int quad = t & 31, rgrp = t >> 5;
    int c4 = quad * 4;
    for (int it = 0; it < 8; ++it) {
        int rl = rgrp + 8 * it;          // 0..63
        int row = r0 + rl;
        float4 acc = {0.f, 0.f, 0.f, 0.f};
        float scale = 0.f;
        if (row < n) {
            int gd = gdbase + row;
            int beg = (gd == 0) ? 0 : OFFS[gd - 1];
            int end = OFFS[gd];
            for (int j = beg; j < end; ++j) {
                int s = sorted[j];
                float w = ns[s];
                float4 v = loadx(x, ((size_t)s << 7) + c4);
                acc.x += v.x * w; acc.y += v.y * w; acc.z += v.z * w; acc.w += v.w * w;
            }
            scale = nd[row];
        }
        ushort4 o;
        o.x = f2bf(acc.x * scale); o.y = f2bf(acc.y * scale);
        o.z = f2bf(acc.z * scale); o.w = f2bf(acc.w * scale);
        *(ushort4*)&Al[rl * 136 + c4] = o;
    }
    __syncthreads();

    int w = t >> 6, lane = t & 63, lm = lane & 15, lg = lane >> 4;
    float rs1[8] = {0.f, 0.f, 0.f, 0.f, 0.f, 0.f, 0.f, 0.f};
    float rs2[8] = {0.f, 0.f, 0.f, 0.f, 0.f, 0.f, 0.f, 0.f};
    int R = r0 + w * 16;

    if (R < n) {
        f32x4 acc[8] = {};
        int abase = (w * 16 + lm) * 136 + lg * 8;
        #pragma unroll
        for (int kbi = 0; kbi < 4; ++kbi) {
            short8 a = *(short8*)&Al[abase + kbi * 32];
            #pragma unroll
            for (int c = 0; c < 8; ++c) {
                short8 b = *(short8*)&Wl[((c * 4 + kbi) * 64 + lane) * 8];
                acc[c] = __builtin_amdgcn_mfma_f32_16x16x32_bf16(a, b, acc[c], 0, 0, 0);
            }
        }
        int rowb = R + lg * 4;
        #pragma unroll
        for (int c = 0; c < 8; ++c) {
            f32x4 v = acc[c];
            rs1[c] += v[0] + v[1] + v[2] + v[3];
            rs2[c] += v[0] * v[0] + v[1] * v[1] + v[2] * v[2] + v[3] * v[3];
            #pragma unroll
            for (int i2 = 0; i2 < 4; ++i2) {
                int row = rowb + i2;
                if (row < n)
                    outp[((size_t)row << 7) + c * 16 + lm] = v[i2];
            }
        }
    }

    #pragma unroll
    for (int c = 0; c < 8; ++c) {
        float s1 = rs1[c], s2 = rs2[c];
        s1 += __shfl_xor(s1, 16); s1 += __shfl_xor(s1, 32);
        s2 += __shfl_xor(s2, 16); s2 += __shfl_xor(s2, 32);
        if (lg == 0) {
            atomicAdd(&Sl[c * 16 + lm], s1);
            atomicAdd(&Sl[128 + c * 16 + lm], s2);
        }
    }
    __syncthreads();
    atomicAdd(&stats[t], Sl[t]);
}

// ---------------------------------------------------------------- BN normalize

// fp32 dst. mode 1: dst += v; mode 2: dst = v + resid
__global__ void k_norm(const float4* __restrict__ out4, const float* __restrict__ stats,
                       const float* __restrict__ gamma, const float* __restrict__ beta,
                       float inv_n, int total4, float4* __restrict__ dst4,
                       const float4* __restrict__ resid4, int mode) {
    __shared__ float sc[128], sh[128];
    int t = threadIdx.x;
    if (t < 128) {
        float mu = stats[t] * inv_n;
        float var = stats[128 + t] * inv_n - mu * mu;
        float s = gamma[t] * rsqrtf(var + 1e-5f);
        sc[t] = s;
        sh[t] = beta[t] - mu * s;
    }
    __syncthreads();
    for (int i = blockIdx.x * blockDim.x + t; i < total4; i += gridDim.x * blockDim.x) {
        int c4 = (i & 31) * 4;
        float4 v = out4[i];
        float4 r;
        r.x = v.x * sc[c4 + 0] + sh[c4 + 0];
        r.y = v.y * sc[c4 + 1] + sh[c4 + 1];
        r.z = v.z * sc[c4 + 2] + sh[c4 + 2];
        r.w = v.w * sc[c4 + 3] + sh[c4 + 3];
        if (mode == 1) {
            float4 d = dst4[i];
            r.x += d.x; r.y += d.y; r.z += d.z; r.w += d.w;
        } else if (mode == 2) {
            float4 d = resid4[i];
            r.x += d.x; r.y += d.y; r.z += d.z; r.w += d.w;
        }
        dst4[i] = r;
    }
}

// bf16 dst. mode 0: dst = v; mode 1: dst += v
__global__ void k_norm_bf(const float4* __restrict__ out4, const float* __restrict__ stats,
                          const float* __restrict__ gamma, const float* __restrict__ beta,
                          float inv_n, int total4, ushort* __restrict__ dst, int mode) {
    __shared__ float sc[128], sh[128];
    int t = threadIdx.x;
    if (t < 128) {
        float mu = stats[t] * inv_n;
        float var = stats[128 + t] * inv_n - mu * mu;
        float s = gamma[t] * rsqrtf(var + 1e-5f);
        sc[t] = s;
        sh[t] = beta[t] - mu * s;
    }
    __syncthreads();
    for (int i = blockIdx.x * blockDim.x + t; i < total4; i += gridDim.x * blockDim.x) {
        int c4 = (i & 31) * 4;
        float4 v = out4[i];
        float4 r;
        r.x = v.x * sc[c4 + 0] + sh[c4 + 0];
        r.y = v.y * sc[c4 + 1] + sh[c4 + 1];
        r.z = v.z * sc[c4 + 2] + sh[c4 + 2];
        r.w = v.w * sc[c4 + 3] + sh[c4 + 3];
        if (mode == 1) {
            ushort4 d = *(const ushort4*)(dst + (size_t)i * 4);
            r.x += bf2f(d.x); r.y += bf2f(d.y); r.z += bf2f(d.z); r.w += bf2f(d.w);
        }
        ushort4 o;
        o.x = f2bf(r.x); o.y = f2bf(r.y); o.z = f2bf(r.z); o.w = f2bf(r.w);
        *(ushort4*)(dst + (size_t)i * 4) = o;
    }
}

// ---------------------------------------------------------------- launch

extern "C" void kernel_launch(void* const* d_in, const int* in_sizes, int n_in,
                              void* d_out, int out_size, void* d_ws, size_t ws_size,
                              hipStream_t stream) {
    static const int NT[3]   = {100000, 150000, 2000};
    static const int RE[9]   = {300000, 300000, 100000, 100000, 150000, 150000, 100000, 150000, 2000};
    static const int RSRC[9] = {0, 1, 0, 2, 1, 2, 0, 1, 2};
    static const int RDST[9] = {1, 0, 2, 0, 2, 1, 0, 1, 2};
    const int TOT_N = 756000;
    const int NB = (TOT_N + 255) / 256;

    const float* feat_in[3] = {(const float*)d_in[0], (const float*)d_in[1], (const float*)d_in[2]};
    const float* W     = (const float*)d_in[3];
    const float* gamma = (const float*)d_in[5];
    const float* beta  = (const float*)d_in[6];
    float* ws  = (float*)d_ws;
    float* out = (float*)d_out;

    int ns_base[9], nd_base[9];
    {
        int s = 0, d = 0;
        for (int r = 0; r < 9; ++r) {
            ns_base[r] = s; s += NT[RSRC[r]];
            nd_base[r] = d; d += NT[RDST[r]];
        }
    }

    // workspace layout (float units; bf16 buffers use half-count)
    const size_t H_A    = 0;                        // 100000*128 bf16
    const size_t H_B    = H_A + 6400000;            // 150000*128 bf16
    const size_t H_G    = H_B + 9600000;            // 2000*128 bf16
    const size_t MBUF   = H_G + 128000;             // small-path m buffer (bf16)
    const size_t OUT    = MBUF + 9600000;           // 150000*128 fp32
    const size_t WT     = OUT + 19200000;           // 18*128*128 bf16
    const size_t STATS  = WT + 147456;              // 18*256 fp32
    const size_t NS     = STATS + 4608;             // 756000
    const size_t ND     = NS + 756000;              // 756000
    const size_t OFFS   = ND + 756000;              // 756000 ints
    const size_t SORTED = OFFS + 756000;            // 1352000 ints
    const size_t BSUM   = SORTED + 1352000;         // scan blocks

    ushort* h_feat[3] = {(ushort*)(ws + H_A), (ushort*)(ws + H_B), (ushort*)(ws + H_G)};
    float* out_feat[3] = {out, out + 12800000, out + 32000000};
    ushort* mbuf   = (ushort*)(ws + MBUF);
    float*  obuf   = ws + OUT;
    ushort* wt     = (ushort*)(ws + WT);
    float*  stats0 = ws + STATS;
    float*  ns_blk = ws + NS;
    float*  nd_blk = ws + ND;
    int*    offs   = (int*)(ws + OFFS);
    int*    sorted = (int*)(ws + SORTED);
    int*    bsum   = (int*)(ws + BSUM);

    // zero stats + degree counters (contiguous)
    hipMemsetAsync(ws + STATS, 0, (4608 + 2 * 756000) * sizeof(float), stream);

    for (int r = 0; r < 9; ++r) {
        const int* src = (const int*)d_in[7 + 2 * r];
        const int* dst = (const int*)d_in[8 + 2 * r];
        k_count<<<(RE[r] + 255) / 256, 256, 0, stream>>>(
            src, dst, RE[r], ns_blk + ns_base[r], nd_blk + nd_base[r]);
    }
    k_scan1<<<NB, 256, 0, stream>>>(nd_blk, offs, bsum, TOT_N);
    k_scan2<<<1, 1024, 0, stream>>>(bsum, NB);
    k_scan3<<<NB, 256, 0, stream>>>(offs, bsum, TOT_N);
    for (int r = 0; r < 9; ++r) {
        const int* src = (const int*)d_in[7 + 2 * r];
        const int* dst = (const int*)d_in[8 + 2 * r];
        k_fill<<<(RE[r] + 255) / 256, 256, 0, stream>>>(
            src, dst, RE[r], offs + nd_base[r], sorted);
    }
    k_rsqrt<<<(2 * TOT_N + 255) / 256, 256, 0, stream>>>(ns_blk, 2 * TOT_N);
    k_prepw<<<(18 * 16384 + 255) / 256, 256, 0, stream>>>(W, wt);

    for (int l = 0; l < 2; ++l) {
        bool touched[3] = {false, false, false};
        for (int r = 0; r < 9; ++r) {
            int st = RSRC[r], dt = RDST[r];
            int n_dst = NT[dt];

            float* stats = stats0 + (size_t)(l * 9 + r) * 256;
            const ushort* wfr = wt + (size_t)(l * 9 + r) * 16384;

            if (dt == 2) {
                // small-n_dst path: parallel gather (32 thr/row) + separate GEMM
                if (l == 0)
                    k_gather<float><<<((size_t)n_dst * 32 + 255) / 256, 256, 0, stream>>>(
                        feat_in[st], ns_blk + ns_base[r], nd_blk + nd_base[r],
                        offs, nd_base[r], sorted, n_dst, mbuf);
                else
                    k_gather<ushort><<<((size_t)n_dst * 32 + 255) / 256, 256, 0, stream>>>(
                        h_feat[st], ns_blk + ns_base[r], nd_blk + nd_base[r],
                        offs, nd_base[r], sorted, n_dst, mbuf);
                k_gemm_mfma<<<(n_dst + 127) / 128, 256, 0, stream>>>(
                    mbuf, wfr, n_dst, obuf, stats);
            } else {
                int nblk = (n_dst + 63) / 64;
                if (l == 0)
                    k_fused<float><<<nblk, 256, 0, stream>>>(
                        feat_in[st], ns_blk + ns_base[r], nd_blk + nd_base[r],
                        offs, nd_base[r], sorted, wfr, n_dst, obuf, stats);
                else
                    k_fused<ushort><<<nblk, 256, 0, stream>>>(
                        h_feat[st], ns_blk + ns_base[r], nd_blk + nd_base[r],
                        offs, nd_base[r], sorted, wfr, n_dst, obuf, stats);
            }

            int total4 = n_dst * 32;
            int ngrid = (total4 + 255) / 256;
            if (ngrid > 2048) ngrid = 2048;
            const float* g = gamma + (size_t)(l * 9 + r) * D;
            const float* b = beta  + (size_t)(l * 9 + r) * D;
            if (l == 0) {
                int mode = touched[dt] ? 1 : 0;
                k_norm_bf<<<ngrid, 256, 0, stream>>>(
                    (const float4*)obuf, stats, g, b, 1.0f / (float)n_dst,
                    total4, h_feat[dt], mode);
            } else {
                int mode = touched[dt] ? 1 : 2;
                k_norm<<<ngrid, 256, 0, stream>>>(
                    (const float4*)obuf, stats, g, b, 1.0f / (float)n_dst,
                    total4, (float4*)out_feat[dt], (const float4*)feat_in[dt], mode);
            }
            touched[dt] = true;
        }
    }
}

// Round 4
// 1935.496 us; speedup vs baseline: 1.7355x; 1.1660x over previous
//
#include <hip/hip_runtime.h>
#include <cstdint>

#define D 128

typedef __attribute__((ext_vector_type(8))) short short8;
typedef __attribute__((ext_vector_type(4))) float f32x4;

__device__ inline ushort f2bf(float f) {
    uint u = __float_as_uint(f);
    uint r = (u + 0x7fffu + ((u >> 16) & 1u)) >> 16;
    return (ushort)r;
}
__device__ inline float bf2f(ushort u) { return __uint_as_float(((uint)u) << 16); }

// ---------------------------------------------------------------- degree / CSR build

__global__ void k_count(const int* __restrict__ src, const int* __restrict__ dst,
                        int E, float* __restrict__ degs, float* __restrict__ degd) {
    int i = blockIdx.x * blockDim.x + threadIdx.x;
    if (i < E) {
        atomicAdd(&degs[src[i]], 1.0f);
        atomicAdd(&degd[dst[i]], 1.0f);
    }
}

__global__ void k_rsqrt(float* __restrict__ p, int n) {
    int i = blockIdx.x * blockDim.x + threadIdx.x;
    if (i < n) {
        float d = p[i];
        p[i] = d > 0.0f ? rsqrtf(d) : 0.0f;
    }
}

__global__ void k_scan1(const float* __restrict__ cnt, int* __restrict__ off,
                        int* __restrict__ bsum, int n) {
    __shared__ int s[256];
    int t = threadIdx.x, i = blockIdx.x * 256 + t;
    int v = (i < n) ? (int)cnt[i] : 0;
    int acc = v;
    s[t] = acc; __syncthreads();
    for (int d = 1; d < 256; d <<= 1) {
        int add = (t >= d) ? s[t - d] : 0;
        __syncthreads();
        acc += add; s[t] = acc; __syncthreads();
    }
    if (i < n) off[i] = acc - v;
    if (t == 255) bsum[blockIdx.x] = acc;
}

__global__ __launch_bounds__(1024) void k_scan2(int* __restrict__ bsum, int nb) {
    __shared__ int s[1024];
    int t = threadIdx.x;
    int i0 = t * 3;
    int v0 = (i0     < nb) ? bsum[i0]     : 0;
    int v1 = (i0 + 1 < nb) ? bsum[i0 + 1] : 0;
    int v2 = (i0 + 2 < nb) ? bsum[i0 + 2] : 0;
    int tot = v0 + v1 + v2;
    int acc = tot;
    s[t] = acc; __syncthreads();
    for (int d = 1; d < 1024; d <<= 1) {
        int add = (t >= d) ? s[t - d] : 0;
        __syncthreads();
        acc += add; s[t] = acc; __syncthreads();
    }
    int base = acc - tot;
    if (i0     < nb) bsum[i0]     = base;
    if (i0 + 1 < nb) bsum[i0 + 1] = base + v0;
    if (i0 + 2 < nb) bsum[i0 + 2] = base + v0 + v1;
}

__global__ void k_scan3(int* __restrict__ off, const int* __restrict__ bsum, int n) {
    int i = blockIdx.x * 256 + threadIdx.x;
    if (i < n) off[i] += bsum[blockIdx.x];
}

__global__ void k_fill(const int* __restrict__ src, const int* __restrict__ dst,
                       int E, int* __restrict__ offs, int* __restrict__ sorted) {
    int e = blockIdx.x * blockDim.x + threadIdx.x;
    if (e < E) {
        int pos = atomicAdd(&offs[dst[e]], 1);
        sorted[pos] = src[e];
    }
}

// W[18][128k][128n] fp32 -> Wf fragment-major bf16:
// Wf[r][c][kbi][lane][e]  (c=col-tile 0..7, kbi=k-block 0..3, lane=lm+16*lg, e=0..7)
//   holds W[k = kbi*32 + lg*8 + e][ncol = c*16 + lm]
__global__ void k_prepw(const float* __restrict__ W, ushort* __restrict__ Wf) {
    int i = blockIdx.x * 256 + threadIdx.x;
    if (i < 18 * 16384) {
        int r = i >> 14, j = i & 16383;
        int e = j & 7, lane = (j >> 3) & 63, kbi = (j >> 9) & 3, c = j >> 11;
        int lm = lane & 15, lg = lane >> 4;
        int k = kbi * 32 + lg * 8 + e, ncol = c * 16 + lm;
        Wf[i] = f2bf(W[(r << 14) + (k << 7) + ncol]);
    }
}

// ---------------------------------------------------------------- gather helpers

__device__ inline float4 loadx(const float* x, size_t idx) { return *(const float4*)(x + idx); }
__device__ inline float4 loadx(const ushort* x, size_t idx) {
    ushort4 u = *(const ushort4*)(x + idx);
    float4 v;
    v.x = bf2f(u.x); v.y = bf2f(u.y); v.z = bf2f(u.z); v.w = bf2f(u.w);
    return v;
}

// separate gather (small-n_dst path): 32 threads per row, one row per thread-group
template <typename XT>
__global__ void k_gather(const XT* __restrict__ x, const float* __restrict__ ns,
                         const float* __restrict__ nd,
                         const int* __restrict__ OFFS, int gdbase,
                         const int* __restrict__ sorted, int n_dst,
                         ushort* __restrict__ m) {
    int gid = blockIdx.x * blockDim.x + threadIdx.x;
    int row = gid >> 5;
    if (row >= n_dst) return;
    int c4 = (gid & 31) * 4;
    int gd = gdbase + row;
    int beg = (gd == 0) ? 0 : OFFS[gd - 1];
    int end = OFFS[gd];
    float4 acc = {0.f, 0.f, 0.f, 0.f};
    for (int j = beg; j < end; ++j) {
        int s = sorted[j];
        float w = ns[s];
        float4 v = loadx(x, ((size_t)s << 7) + c4);
        acc.x += v.x * w; acc.y += v.y * w; acc.z += v.z * w; acc.w += v.w * w;
    }
    float sc = nd[row];
    ushort4 o;
    o.x = f2bf(acc.x * sc); o.y = f2bf(acc.y * sc);
    o.z = f2bf(acc.z * sc); o.w = f2bf(acc.w * sc);
    *(ushort4*)(m + ((size_t)row << 7) + c4) = o;
}

// separate GEMM (small-n_dst path): 4 waves, each owns an independent 32-row tile
__global__ __launch_bounds__(256) void k_gemm_mfma(
    const ushort* __restrict__ mb, const ushort* __restrict__ Wf,
    int n, float* __restrict__ outp, float* __restrict__ stats) {
    __shared__ ushort Wl[16384];
    __shared__ float Sl[256];
    int t = threadIdx.x;
    int w = t >> 6, lane = t & 63, lm = lane & 15, lg = lane >> 4;
    Sl[t] = 0.0f;

    #pragma unroll
    for (int i = 0; i < 8; ++i) {
        int ci = t + 256 * i;
        *(short8*)&Wl[ci * 8] = *(const short8*)&Wf[ci * 8];
    }
    __syncthreads();

    int R = (blockIdx.x * 4 + w) * 32;
    float rs1[8] = {0.f, 0.f, 0.f, 0.f, 0.f, 0.f, 0.f, 0.f};
    float rs2[8] = {0.f, 0.f, 0.f, 0.f, 0.f, 0.f, 0.f, 0.f};

    if (R < n) {
        f32x4 acc[2][8] = {};
        int r0 = R + lm, r1 = R + 16 + lm;
        const ushort* a0p = mb + (((size_t)r0) << 7) + lg * 8;
        const ushort* a1p = mb + (((size_t)r1) << 7) + lg * 8;
        bool v0 = r0 < n, v1 = r1 < n;
        #pragma unroll
        for (int kbi = 0; kbi < 4; ++kbi) {
            short8 a0 = {}, a1 = {};
            if (v0) a0 = *(const short8*)(a0p + kbi * 32);
            if (v1) a1 = *(const short8*)(a1p + kbi * 32);
            #pragma unroll
            for (int c = 0; c < 8; ++c) {
                short8 b = *(short8*)&Wl[((c * 4 + kbi) * 64 + lane) * 8];
                acc[0][c] = __builtin_amdgcn_mfma_f32_16x16x32_bf16(a0, b, acc[0][c], 0, 0, 0);
                acc[1][c] = __builtin_amdgcn_mfma_f32_16x16x32_bf16(a1, b, acc[1][c], 0, 0, 0);
            }
        }
        #pragma unroll
        for (int m = 0; m < 2; ++m) {
            int rowb = R + m * 16 + lg * 4;
            #pragma unroll
            for (int c = 0; c < 8; ++c) {
                f32x4 v = acc[m][c];
                rs1[c] += v[0] + v[1] + v[2] + v[3];
                rs2[c] += v[0] * v[0] + v[1] * v[1] + v[2] * v[2] + v[3] * v[3];
                #pragma unroll
                for (int i2 = 0; i2 < 4; ++i2) {
                    int row = rowb + i2;
                    if (row < n)
                        outp[((size_t)row << 7) + c * 16 + lm] = v[i2];
                }
            }
        }
    }

    #pragma unroll
    for (int c = 0; c < 8; ++c) {
        float s1 = rs1[c], s2 = rs2[c];
        s1 += __shfl_xor(s1, 16); s1 += __shfl_xor(s1, 32);
        s2 += __shfl_xor(s2, 16); s2 += __shfl_xor(s2, 32);
        if (lg == 0) {
            atomicAdd(&Sl[c * 16 + lm], s1);
            atomicAdd(&Sl[128 + c * 16 + lm], s2);
        }
    }
    __syncthreads();
    atomicAdd(&stats[t], Sl[t]);
}

// ---------------------------------------------------------------- fused gather + MFMA (big-n_dst path)

// Each wave owns 16 independent rows. Lane (lm,lg) gathers row R+lm, channel
// octets (kbi*4+lg)*8 for kbi=0..3 -- exactly its MFMA A-fragment slots.
// Gather accumulates in 32 registers, converts to 4 bf16 short8 frags
// in-register: no A tile in LDS, no mbuf round trip, no per-thread row
// serialization. LDS holds only W (32 KB, conflict-free fragment-major).
template <typename XT>
__global__ __launch_bounds__(256) void k_fused2(
    const XT* __restrict__ x, const float* __restrict__ ns,
    const float* __restrict__ nd,
    const int* __restrict__ OFFS, int gdbase,
    const int* __restrict__ sorted,
    const ushort* __restrict__ Wf,
    int n, float* __restrict__ outp, float* __restrict__ stats) {
    __shared__ ushort Wl[16384];
    __shared__ float Sl[256];
    int t = threadIdx.x;
    Sl[t] = 0.0f;

    #pragma unroll
    for (int i = 0; i < 8; ++i) {
        int ci = t + 256 * i;
        *(short8*)&Wl[ci * 8] = *(const short8*)&Wf[ci * 8];
    }

    int w = t >> 6, lane = t & 63, lm = lane & 15, lg = lane >> 4;
    int R = blockIdx.x * 64 + w * 16;
    int row = R + lm;

    float a[4][8] = {};
    float scale = 0.0f;
    if (row < n) {
        int gd = gdbase + row;
        int beg = (gd == 0) ? 0 : OFFS[gd - 1];
        int end = OFFS[gd];
        for (int j = beg; j < end; ++j) {
            int s = sorted[j];
            float wgt = ns[s];
            size_t xb = (size_t)s << 7;
            #pragma unroll
            for (int kbi = 0; kbi < 4; ++kbi) {
                int cb = (kbi * 4 + lg) * 8;
                float4 u0 = loadx(x, xb + cb);
                float4 u1 = loadx(x, xb + cb + 4);
                a[kbi][0] += u0.x * wgt; a[kbi][1] += u0.y * wgt;
                a[kbi][2] += u0.z * wgt; a[kbi][3] += u0.w * wgt;
                a[kbi][4] += u1.x * wgt; a[kbi][5] += u1.y * wgt;
                a[kbi][6] += u1.z * wgt; a[kbi][7] += u1.w * wgt;
            }
        }
        scale = nd[row];
    }

    // convert to bf16 A-fragments in-register
    short8 af[4];
    #pragma unroll
    for (int kbi = 0; kbi < 4; ++kbi) {
        #pragma unroll
        for (int e = 0; e < 8; ++e)
            af[kbi][e] = (short)f2bf(a[kbi][e] * scale);
    }

    __syncthreads();   // Wl ready

    float rs1[8] = {0.f, 0.f, 0.f, 0.f, 0.f, 0.f, 0.f, 0.f};
    float rs2[8] = {0.f, 0.f, 0.f, 0.f, 0.f, 0.f, 0.f, 0.f};

    if (R < n) {
        f32x4 acc[8] = {};
        #pragma unroll
        for (int kbi = 0; kbi < 4; ++kbi) {
            #pragma unroll
            for (int c = 0; c < 8; ++c) {
                short8 b = *(short8*)&Wl[((c * 4 + kbi) * 64 + lane) * 8];
                acc[c] = __builtin_amdgcn_mfma_f32_16x16x32_bf16(af[kbi], b, acc[c], 0, 0, 0);
            }
        }
        int rowb = R + lg * 4;
        #pragma unroll
        for (int c = 0; c < 8; ++c) {
            f32x4 v = acc[c];
            rs1[c] += v[0] + v[1] + v[2] + v[3];
            rs2[c] += v[0] * v[0] + v[1] * v[1] + v[2] * v[2] + v[3] * v[3];
            #pragma unroll
            for (int i2 = 0; i2 < 4; ++i2) {
                int crow = rowb + i2;
                if (crow < n)
                    outp[((size_t)crow << 7) + c * 16 + lm] = v[i2];
            }
        }
    }

    #pragma unroll
    for (int c = 0; c < 8; ++c) {
        float s1 = rs1[c], s2 = rs2[c];
        s1 += __shfl_xor(s1, 16); s1 += __shfl_xor(s1, 32);
        s2 += __shfl_xor(s2, 16); s2 += __shfl_xor(s2, 32);
        if (lg == 0) {
            atomicAdd(&Sl[c * 16 + lm], s1);
            atomicAdd(&Sl[128 + c * 16 + lm], s2);
        }
    }
    __syncthreads();
    atomicAdd(&stats[t], Sl[t]);
}

// ---------------------------------------------------------------- BN normalize

// fp32 dst. mode 1: dst += v; mode 2: dst = v + resid
__global__ void k_norm(const float4* __restrict__ out4, const float* __restrict__ stats,
                       const float* __restrict__ gamma, const float* __restrict__ beta,
                       float inv_n, int total4, float4* __restrict__ dst4,
                       const float4* __restrict__ resid4, int mode) {
    __shared__ float sc[128], sh[128];
    int t = threadIdx.x;
    if (t < 128) {
        float mu = stats[t] * inv_n;
        float var = stats[128 + t] * inv_n - mu * mu;
        float s = gamma[t] * rsqrtf(var + 1e-5f);
        sc[t] = s;
        sh[t] = beta[t] - mu * s;
    }
    __syncthreads();
    for (int i = blockIdx.x * blockDim.x + t; i < total4; i += gridDim.x * blockDim.x) {
        int c4 = (i & 31) * 4;
        float4 v = out4[i];
        float4 r;
        r.x = v.x * sc[c4 + 0] + sh[c4 + 0];
        r.y = v.y * sc[c4 + 1] + sh[c4 + 1];
        r.z = v.z * sc[c4 + 2] + sh[c4 + 2];
        r.w = v.w * sc[c4 + 3] + sh[c4 + 3];
        if (mode == 1) {
            float4 d = dst4[i];
            r.x += d.x; r.y += d.y; r.z += d.z; r.w += d.w;
        } else if (mode == 2) {
            float4 d = resid4[i];
            r.x += d.x; r.y += d.y; r.z += d.z; r.w += d.w;
        }
        dst4[i] = r;
    }
}

// bf16 dst. mode 0: dst = v; mode 1: dst += v
__global__ void k_norm_bf(const float4* __restrict__ out4, const float* __restrict__ stats,
                          const float* __restrict__ gamma, const float* __restrict__ beta,
                          float inv_n, int total4, ushort* __restrict__ dst, int mode) {
    __shared__ float sc[128], sh[128];
    int t = threadIdx.x;
    if (t < 128) {
        float mu = stats[t] * inv_n;
        float var = stats[128 + t] * inv_n - mu * mu;
        float s = gamma[t] * rsqrtf(var + 1e-5f);
        sc[t] = s;
        sh[t] = beta[t] - mu * s;
    }
    __syncthreads();
    for (int i = blockIdx.x * blockDim.x + t; i < total4; i += gridDim.x * blockDim.x) {
        int c4 = (i & 31) * 4;
        float4 v = out4[i];
        float4 r;
        r.x = v.x * sc[c4 + 0] + sh[c4 + 0];
        r.y = v.y * sc[c4 + 1] + sh[c4 + 1];
        r.z = v.z * sc[c4 + 2] + sh[c4 + 2];
        r.w = v.w * sc[c4 + 3] + sh[c4 + 3];
        if (mode == 1) {
            ushort4 d = *(const ushort4*)(dst + (size_t)i * 4);
            r.x += bf2f(d.x); r.y += bf2f(d.y); r.z += bf2f(d.z); r.w += bf2f(d.w);
        }
        ushort4 o;
        o.x = f2bf(r.x); o.y = f2bf(r.y); o.z = f2bf(r.z); o.w = f2bf(r.w);
        *(ushort4*)(dst + (size_t)i * 4) = o;
    }
}

// ---------------------------------------------------------------- launch

extern "C" void kernel_launch(void* const* d_in, const int* in_sizes, int n_in,
                              void* d_out, int out_size, void* d_ws, size_t ws_size,
                              hipStream_t stream) {
    static const int NT[3]   = {100000, 150000, 2000};
    static const int RE[9]   = {300000, 300000, 100000, 100000, 150000, 150000, 100000, 150000, 2000};
    static const int RSRC[9] = {0, 1, 0, 2, 1, 2, 0, 1, 2};
    static const int RDST[9] = {1, 0, 2, 0, 2, 1, 0, 1, 2};
    const int TOT_N = 756000;
    const int NB = (TOT_N + 255) / 256;

    const float* feat_in[3] = {(const float*)d_in[0], (const float*)d_in[1], (const float*)d_in[2]};
    const float* W     = (const float*)d_in[3];
    const float* gamma = (const float*)d_in[5];
    const float* beta  = (const float*)d_in[6];
    float* ws  = (float*)d_ws;
    float* out = (float*)d_out;

    int ns_base[9], nd_base[9];
    {
        int s = 0, d = 0;
        for (int r = 0; r < 9; ++r) {
            ns_base[r] = s; s += NT[RSRC[r]];
            nd_base[r] = d; d += NT[RDST[r]];
        }
    }

    // workspace layout (float units; bf16 buffers use half-count)
    const size_t H_A    = 0;                        // 100000*128 bf16
    const size_t H_B    = H_A + 6400000;            // 150000*128 bf16
    const size_t H_G    = H_B + 9600000;            // 2000*128 bf16
    const size_t MBUF   = H_G + 128000;             // small-path m buffer (bf16)
    const size_t OUT    = MBUF + 9600000;           // 150000*128 fp32
    const size_t WT     = OUT + 19200000;           // 18*128*128 bf16
    const size_t STATS  = WT + 147456;              // 18*256 fp32
    const size_t NS     = STATS + 4608;             // 756000
    const size_t ND     = NS + 756000;              // 756000
    const size_t OFFS   = ND + 756000;              // 756000 ints
    const size_t SORTED = OFFS + 756000;            // 1352000 ints
    const size_t BSUM   = SORTED + 1352000;         // scan blocks

    ushort* h_feat[3] = {(ushort*)(ws + H_A), (ushort*)(ws + H_B), (ushort*)(ws + H_G)};
    float* out_feat[3] = {out, out + 12800000, out + 32000000};
    ushort* mbuf   = (ushort*)(ws + MBUF);
    float*  obuf   = ws + OUT;
    ushort* wt     = (ushort*)(ws + WT);
    float*  stats0 = ws + STATS;
    float*  ns_blk = ws + NS;
    float*  nd_blk = ws + ND;
    int*    offs   = (int*)(ws + OFFS);
    int*    sorted = (int*)(ws + SORTED);
    int*    bsum   = (int*)(ws + BSUM);

    // zero stats + degree counters (contiguous)
    hipMemsetAsync(ws + STATS, 0, (4608 + 2 * 756000) * sizeof(float), stream);

    for (int r = 0; r < 9; ++r) {
        const int* src = (const int*)d_in[7 + 2 * r];
        const int* dst = (const int*)d_in[8 + 2 * r];
        k_count<<<(RE[r] + 255) / 256, 256, 0, stream>>>(
            src, dst, RE[r], ns_blk + ns_base[r], nd_blk + nd_base[r]);
    }
    k_scan1<<<NB, 256, 0, stream>>>(nd_blk, offs, bsum, TOT_N);
    k_scan2<<<1, 1024, 0, stream>>>(bsum, NB);
    k_scan3<<<NB, 256, 0, stream>>>(offs, bsum, TOT_N);
    for (int r = 0; r < 9; ++r) {
        const int* src = (const int*)d_in[7 + 2 * r];
        const int* dst = (const int*)d_in[8 + 2 * r];
        k_fill<<<(RE[r] + 255) / 256, 256, 0, stream>>>(
            src, dst, RE[r], offs + nd_base[r], sorted);
    }
    k_rsqrt<<<(2 * TOT_N + 255) / 256, 256, 0, stream>>>(ns_blk, 2 * TOT_N);
    k_prepw<<<(18 * 16384 + 255) / 256, 256, 0, stream>>>(W, wt);

    for (int l = 0; l < 2; ++l) {
        bool touched[3] = {false, false, false};
        for (int r = 0; r < 9; ++r) {
            int st = RSRC[r], dt = RDST[r];
            int n_dst = NT[dt];

            float* stats = stats0 + (size_t)(l * 9 + r) * 256;
            const ushort* wfr = wt + (size_t)(l * 9 + r) * 16384;

            if (dt == 2) {
                // small-n_dst path: parallel gather (32 thr/row) + separate GEMM
                if (l == 0)
                    k_gather<float><<<((size_t)n_dst * 32 + 255) / 256, 256, 0, stream>>>(
                        feat_in[st], ns_blk + ns_base[r], nd_blk + nd_base[r],
                        offs, nd_base[r], sorted, n_dst, mbuf);
                else
                    k_gather<ushort><<<((size_t)n_dst * 32 + 255) / 256, 256, 0, stream>>>(
                        h_feat[st], ns_blk + ns_base[r], nd_blk + nd_base[r],
                        offs, nd_base[r], sorted, n_dst, mbuf);
                k_gemm_mfma<<<(n_dst + 127) / 128, 256, 0, stream>>>(
                    mbuf, wfr, n_dst, obuf, stats);
            } else {
                int nblk = (n_dst + 63) / 64;
                if (l == 0)
                    k_fused2<float><<<nblk, 256, 0, stream>>>(
                        feat_in[st], ns_blk + ns_base[r], nd_blk + nd_base[r],
                        offs, nd_base[r], sorted, wfr, n_dst, obuf, stats);
                else
                    k_fused2<ushort><<<nblk, 256, 0, stream>>>(
                        h_feat[st], ns_blk + ns_base[r], nd_blk + nd_base[r],
                        offs, nd_base[r], sorted, wfr, n_dst, obuf, stats);
            }

            int total4 = n_dst * 32;
            int ngrid = (total4 + 255) / 256;
            if (ngrid > 2048) ngrid = 2048;
            const float* g = gamma + (size_t)(l * 9 + r) * D;
            const float* b = beta  + (size_t)(l * 9 + r) * D;
            if (l == 0) {
                int mode = touched[dt] ? 1 : 0;
                k_norm_bf<<<ngrid, 256, 0, stream>>>(
                    (const float4*)obuf, stats, g, b, 1.0f / (float)n_dst,
                    total4, h_feat[dt], mode);
            } else {
                int mode = touched[dt] ? 1 : 2;
                k_norm<<<ngrid, 256, 0, stream>>>(
                    (const float4*)obuf, stats, g, b, 1.0f / (float)n_dst,
                    total4, (float4*)out_feat[dt], (const float4*)feat_in[dt], mode);
            }
            touched[dt] = true;
        }
    }
}

// Round 5
// 1736.477 us; speedup vs baseline: 1.9345x; 1.1146x over previous
//
#include <hip/hip_runtime.h>
#include <cstdint>

#define D 128

typedef __attribute__((ext_vector_type(8))) short short8;
typedef __attribute__((ext_vector_type(4))) float f32x4;

__device__ inline ushort f2bf(float f) {
    uint u = __float_as_uint(f);
    uint r = (u + 0x7fffu + ((u >> 16) & 1u)) >> 16;
    return (ushort)r;
}
__device__ inline float bf2f(ushort u) { return __uint_as_float(((uint)u) << 16); }

// ---------------------------------------------------------------- degree / CSR build

__global__ void k_count(const int* __restrict__ src, const int* __restrict__ dst,
                        int E, float* __restrict__ degs, float* __restrict__ degd) {
    int i = blockIdx.x * blockDim.x + threadIdx.x;
    if (i < E) {
        atomicAdd(&degs[src[i]], 1.0f);
        atomicAdd(&degd[dst[i]], 1.0f);
    }
}

__global__ void k_rsqrt(float* __restrict__ p, int n) {
    int i = blockIdx.x * blockDim.x + threadIdx.x;
    if (i < n) {
        float d = p[i];
        p[i] = d > 0.0f ? rsqrtf(d) : 0.0f;
    }
}

__global__ void k_scan1(const float* __restrict__ cnt, int* __restrict__ off,
                        int* __restrict__ bsum, int n) {
    __shared__ int s[256];
    int t = threadIdx.x, i = blockIdx.x * 256 + t;
    int v = (i < n) ? (int)cnt[i] : 0;
    int acc = v;
    s[t] = acc; __syncthreads();
    for (int d = 1; d < 256; d <<= 1) {
        int add = (t >= d) ? s[t - d] : 0;
        __syncthreads();
        acc += add; s[t] = acc; __syncthreads();
    }
    if (i < n) off[i] = acc - v;
    if (t == 255) bsum[blockIdx.x] = acc;
}

__global__ __launch_bounds__(1024) void k_scan2(int* __restrict__ bsum, int nb) {
    __shared__ int s[1024];
    int t = threadIdx.x;
    int i0 = t * 3;
    int v0 = (i0     < nb) ? bsum[i0]     : 0;
    int v1 = (i0 + 1 < nb) ? bsum[i0 + 1] : 0;
    int v2 = (i0 + 2 < nb) ? bsum[i0 + 2] : 0;
    int tot = v0 + v1 + v2;
    int acc = tot;
    s[t] = acc; __syncthreads();
    for (int d = 1; d < 1024; d <<= 1) {
        int add = (t >= d) ? s[t - d] : 0;
        __syncthreads();
        acc += add; s[t] = acc; __syncthreads();
    }
    int base = acc - tot;
    if (i0     < nb) bsum[i0]     = base;
    if (i0 + 1 < nb) bsum[i0 + 1] = base + v0;
    if (i0 + 2 < nb) bsum[i0 + 2] = base + v0 + v1;
}

__global__ void k_scan3(int* __restrict__ off, const int* __restrict__ bsum, int n) {
    int i = blockIdx.x * 256 + threadIdx.x;
    if (i < n) off[i] += bsum[blockIdx.x];
}

__global__ void k_fill(const int* __restrict__ src, const int* __restrict__ dst,
                       int E, int* __restrict__ offs, int* __restrict__ sorted) {
    int e = blockIdx.x * blockDim.x + threadIdx.x;
    if (e < E) {
        int pos = atomicAdd(&offs[dst[e]], 1);
        sorted[pos] = src[e];
    }
}

// W[18][128k][128n] fp32 -> Wf fragment-major bf16:
// Wf[r][c][kbi][lane][e]  (c=col-tile 0..7, kbi=k-block 0..3, lane=lm+16*lg, e=0..7)
//   holds W[k = kbi*32 + lg*8 + e][ncol = c*16 + lm]
__global__ void k_prepw(const float* __restrict__ W, ushort* __restrict__ Wf) {
    int i = blockIdx.x * 256 + threadIdx.x;
    if (i < 18 * 16384) {
        int r = i >> 14, j = i & 16383;
        int e = j & 7, lane = (j >> 3) & 63, kbi = (j >> 9) & 3, c = j >> 11;
        int lm = lane & 15, lg = lane >> 4;
        int k = kbi * 32 + lg * 8 + e, ncol = c * 16 + lm;
        Wf[i] = f2bf(W[(r << 14) + (k << 7) + ncol]);
    }
}

// ---------------------------------------------------------------- gather helpers

__device__ inline float4 loadx(const float* x, size_t idx) { return *(const float4*)(x + idx); }
__device__ inline float4 loadx(const ushort* x, size_t idx) {
    ushort4 u = *(const ushort4*)(x + idx);
    float4 v;
    v.x = bf2f(u.x); v.y = bf2f(u.y); v.z = bf2f(u.z); v.w = bf2f(u.w);
    return v;
}

// separate gather (small-n_dst path): 32 threads per row, one row per thread-group
template <typename XT>
__global__ void k_gather(const XT* __restrict__ x, const float* __restrict__ ns,
                         const float* __restrict__ nd,
                         const int* __restrict__ OFFS, int gdbase,
                         const int* __restrict__ sorted, int n_dst,
                         ushort* __restrict__ m) {
    int gid = blockIdx.x * blockDim.x + threadIdx.x;
    int row = gid >> 5;
    if (row >= n_dst) return;
    int c4 = (gid & 31) * 4;
    int gd = gdbase + row;
    int beg = (gd == 0) ? 0 : OFFS[gd - 1];
    int end = OFFS[gd];
    float4 acc = {0.f, 0.f, 0.f, 0.f};
    for (int j = beg; j < end; ++j) {
        int s = sorted[j];
        float w = ns[s];
        float4 v = loadx(x, ((size_t)s << 7) + c4);
        acc.x += v.x * w; acc.y += v.y * w; acc.z += v.z * w; acc.w += v.w * w;
    }
    float sc = nd[row];
    ushort4 o;
    o.x = f2bf(acc.x * sc); o.y = f2bf(acc.y * sc);
    o.z = f2bf(acc.z * sc); o.w = f2bf(acc.w * sc);
    *(ushort4*)(m + ((size_t)row << 7) + c4) = o;
}

// separate GEMM (small-n_dst path): 4 waves, each owns an independent 32-row tile
__global__ __launch_bounds__(256) void k_gemm_mfma(
    const ushort* __restrict__ mb, const ushort* __restrict__ Wf,
    int n, float* __restrict__ outp, float* __restrict__ stats) {
    __shared__ ushort Wl[16384];
    __shared__ float Sl[256];
    int t = threadIdx.x;
    int w = t >> 6, lane = t & 63, lm = lane & 15, lg = lane >> 4;
    Sl[t] = 0.0f;

    #pragma unroll
    for (int i = 0; i < 8; ++i) {
        int ci = t + 256 * i;
        *(short8*)&Wl[ci * 8] = *(const short8*)&Wf[ci * 8];
    }
    __syncthreads();

    int R = (blockIdx.x * 4 + w) * 32;
    float rs1[8] = {0.f, 0.f, 0.f, 0.f, 0.f, 0.f, 0.f, 0.f};
    float rs2[8] = {0.f, 0.f, 0.f, 0.f, 0.f, 0.f, 0.f, 0.f};

    if (R < n) {
        f32x4 acc[2][8] = {};
        int r0 = R + lm, r1 = R + 16 + lm;
        const ushort* a0p = mb + (((size_t)r0) << 7) + lg * 8;
        const ushort* a1p = mb + (((size_t)r1) << 7) + lg * 8;
        bool v0 = r0 < n, v1 = r1 < n;
        #pragma unroll
        for (int kbi = 0; kbi < 4; ++kbi) {
            short8 a0 = {}, a1 = {};
            if (v0) a0 = *(const short8*)(a0p + kbi * 32);
            if (v1) a1 = *(const short8*)(a1p + kbi * 32);
            #pragma unroll
            for (int c = 0; c < 8; ++c) {
                short8 b = *(short8*)&Wl[((c * 4 + kbi) * 64 + lane) * 8];
                acc[0][c] = __builtin_amdgcn_mfma_f32_16x16x32_bf16(a0, b, acc[0][c], 0, 0, 0);
                acc[1][c] = __builtin_amdgcn_mfma_f32_16x16x32_bf16(a1, b, acc[1][c], 0, 0, 0);
            }
        }
        #pragma unroll
        for (int m = 0; m < 2; ++m) {
            int rowb = R + m * 16 + lg * 4;
            #pragma unroll
            for (int c = 0; c < 8; ++c) {
                f32x4 v = acc[m][c];
                rs1[c] += v[0] + v[1] + v[2] + v[3];
                rs2[c] += v[0] * v[0] + v[1] * v[1] + v[2] * v[2] + v[3] * v[3];
                #pragma unroll
                for (int i2 = 0; i2 < 4; ++i2) {
                    int row = rowb + i2;
                    if (row < n)
                        outp[((size_t)row << 7) + c * 16 + lm] = v[i2];
                }
            }
        }
    }

    #pragma unroll
    for (int c = 0; c < 8; ++c) {
        float s1 = rs1[c], s2 = rs2[c];
        s1 += __shfl_xor(s1, 16); s1 += __shfl_xor(s1, 32);
        s2 += __shfl_xor(s2, 16); s2 += __shfl_xor(s2, 32);
        if (lg == 0) {
            atomicAdd(&Sl[c * 16 + lm], s1);
            atomicAdd(&Sl[128 + c * 16 + lm], s2);
        }
    }
    __syncthreads();
    atomicAdd(&stats[t], Sl[t]);
}

// ---------------------------------------------------------------- fused gather + MFMA (big-n_dst path)

// 512 threads = 8 waves per block, 128 rows/block. Each wave owns 16
// independent rows; lane (lm,lg) gathers row R+lm, channel octets
// (kbi*4+lg)*8 (kbi=0..3) -- exactly its MFMA A-fragment slots, accumulated
// in registers and converted to bf16 in-register. LDS holds only W (32 KB):
// 4 blocks/CU x 8 waves = 32 waves/CU (full wave cap) to hide the
// dependent-load gather chain.
template <typename XT>
__global__ __launch_bounds__(512) void k_fused2(
    const XT* __restrict__ x, const float* __restrict__ ns,
    const float* __restrict__ nd,
    const int* __restrict__ OFFS, int gdbase,
    const int* __restrict__ sorted,
    const ushort* __restrict__ Wf,
    int n, float* __restrict__ outp, float* __restrict__ stats) {
    __shared__ ushort Wl[16384];
    __shared__ float Sl[256];
    int t = threadIdx.x;
    if (t < 256) Sl[t] = 0.0f;

    #pragma unroll
    for (int i = 0; i < 4; ++i) {
        int ci = t + 512 * i;
        *(short8*)&Wl[ci * 8] = *(const short8*)&Wf[ci * 8];
    }

    int w = t >> 6, lane = t & 63, lm = lane & 15, lg = lane >> 4;
    int R = blockIdx.x * 128 + w * 16;
    int row = R + lm;

    float a[4][8] = {};
    float scale = 0.0f;
    if (row < n) {
        int gd = gdbase + row;
        int beg = (gd == 0) ? 0 : OFFS[gd - 1];
        int end = OFFS[gd];
        for (int j = beg; j < end; ++j) {
            int s = sorted[j];
            float wgt = ns[s];
            size_t xb = (size_t)s << 7;
            #pragma unroll
            for (int kbi = 0; kbi < 4; ++kbi) {
                int cb = (kbi * 4 + lg) * 8;
                float4 u0 = loadx(x, xb + cb);
                float4 u1 = loadx(x, xb + cb + 4);
                a[kbi][0] += u0.x * wgt; a[kbi][1] += u0.y * wgt;
                a[kbi][2] += u0.z * wgt; a[kbi][3] += u0.w * wgt;
                a[kbi][4] += u1.x * wgt; a[kbi][5] += u1.y * wgt;
                a[kbi][6] += u1.z * wgt; a[kbi][7] += u1.w * wgt;
            }
        }
        scale = nd[row];
    }

    // convert to bf16 A-fragments in-register
    short8 af[4];
    #pragma unroll
    for (int kbi = 0; kbi < 4; ++kbi) {
        #pragma unroll
        for (int e = 0; e < 8; ++e)
            af[kbi][e] = (short)f2bf(a[kbi][e] * scale);
    }

    __syncthreads();   // Wl ready

    float rs1[8] = {0.f, 0.f, 0.f, 0.f, 0.f, 0.f, 0.f, 0.f};
    float rs2[8] = {0.f, 0.f, 0.f, 0.f, 0.f, 0.f, 0.f, 0.f};

    if (R < n) {
        f32x4 acc[8] = {};
        #pragma unroll
        for (int kbi = 0; kbi < 4; ++kbi) {
            #pragma unroll
            for (int c = 0; c < 8; ++c) {
                short8 b = *(short8*)&Wl[((c * 4 + kbi) * 64 + lane) * 8];
                acc[c] = __builtin_amdgcn_mfma_f32_16x16x32_bf16(af[kbi], b, acc[c], 0, 0, 0);
            }
        }
        int rowb = R + lg * 4;
        #pragma unroll
        for (int c = 0; c < 8; ++c) {
            f32x4 v = acc[c];
            rs1[c] += v[0] + v[1] + v[2] + v[3];
            rs2[c] += v[0] * v[0] + v[1] * v[1] + v[2] * v[2] + v[3] * v[3];
            #pragma unroll
            for (int i2 = 0; i2 < 4; ++i2) {
                int crow = rowb + i2;
                if (crow < n)
                    outp[((size_t)crow << 7) + c * 16 + lm] = v[i2];
            }
        }
    }

    #pragma unroll
    for (int c = 0; c < 8; ++c) {
        float s1 = rs1[c], s2 = rs2[c];
        s1 += __shfl_xor(s1, 16); s1 += __shfl_xor(s1, 32);
        s2 += __shfl_xor(s2, 16); s2 += __shfl_xor(s2, 32);
        if (lg == 0) {
            atomicAdd(&Sl[c * 16 + lm], s1);
            atomicAdd(&Sl[128 + c * 16 + lm], s2);
        }
    }
    __syncthreads();
    if (t < 256) atomicAdd(&stats[t], Sl[t]);
}

// ---------------------------------------------------------------- BN normalize

// fp32 dst. mode 1: dst += v; mode 2: dst = v + resid
__global__ void k_norm(const float4* __restrict__ out4, const float* __restrict__ stats,
                       const float* __restrict__ gamma, const float* __restrict__ beta,
                       float inv_n, int total4, float4* __restrict__ dst4,
                       const float4* __restrict__ resid4, int mode) {
    __shared__ float sc[128], sh[128];
    int t = threadIdx.x;
    if (t < 128) {
        float mu = stats[t] * inv_n;
        float var = stats[128 + t] * inv_n - mu * mu;
        float s = gamma[t] * rsqrtf(var + 1e-5f);
        sc[t] = s;
        sh[t] = beta[t] - mu * s;
    }
    __syncthreads();
    for (int i = blockIdx.x * blockDim.x + t; i < total4; i += gridDim.x * blockDim.x) {
        int c4 = (i & 31) * 4;
        float4 v = out4[i];
        float4 r;
        r.x = v.x * sc[c4 + 0] + sh[c4 + 0];
        r.y = v.y * sc[c4 + 1] + sh[c4 + 1];
        r.z = v.z * sc[c4 + 2] + sh[c4 + 2];
        r.w = v.w * sc[c4 + 3] + sh[c4 + 3];
        if (mode == 1) {
            float4 d = dst4[i];
            r.x += d.x; r.y += d.y; r.z += d.z; r.w += d.w;
        } else if (mode == 2) {
            float4 d = resid4[i];
            r.x += d.x; r.y += d.y; r.z += d.z; r.w += d.w;
        }
        dst4[i] = r;
    }
}

// bf16 dst. mode 0: dst = v; mode 1: dst += v
__global__ void k_norm_bf(const float4* __restrict__ out4, const float* __restrict__ stats,
                          const float* __restrict__ gamma, const float* __restrict__ beta,
                          float inv_n, int total4, ushort* __restrict__ dst, int mode) {
    __shared__ float sc[128], sh[128];
    int t = threadIdx.x;
    if (t < 128) {
        float mu = stats[t] * inv_n;
        float var = stats[128 + t] * inv_n - mu * mu;
        float s = gamma[t] * rsqrtf(var + 1e-5f);
        sc[t] = s;
        sh[t] = beta[t] - mu * s;
    }
    __syncthreads();
    for (int i = blockIdx.x * blockDim.x + t; i < total4; i += gridDim.x * blockDim.x) {
        int c4 = (i & 31) * 4;
        float4 v = out4[i];
        float4 r;
        r.x = v.x * sc[c4 + 0] + sh[c4 + 0];
        r.y = v.y * sc[c4 + 1] + sh[c4 + 1];
        r.z = v.z * sc[c4 + 2] + sh[c4 + 2];
        r.w = v.w * sc[c4 + 3] + sh[c4 + 3];
        if (mode == 1) {
            ushort4 d = *(const ushort4*)(dst + (size_t)i * 4);
            r.x += bf2f(d.x); r.y += bf2f(d.y); r.z += bf2f(d.z); r.w += bf2f(d.w);
        }
        ushort4 o;
        o.x = f2bf(r.x); o.y = f2bf(r.y); o.z = f2bf(r.z); o.w = f2bf(r.w);
        *(ushort4*)(dst + (size_t)i * 4) = o;
    }
}

// ---------------------------------------------------------------- launch

extern "C" void kernel_launch(void* const* d_in, const int* in_sizes, int n_in,
                              void* d_out, int out_size, void* d_ws, size_t ws_size,
                              hipStream_t stream) {
    static const int NT[3]   = {100000, 150000, 2000};
    static const int RE[9]   = {300000, 300000, 100000, 100000, 150000, 150000, 100000, 150000, 2000};
    static const int RSRC[9] = {0, 1, 0, 2, 1, 2, 0, 1, 2};
    static const int RDST[9] = {1, 0, 2, 0, 2, 1, 0, 1, 2};
    const int TOT_N = 756000;
    const int NB = (TOT_N + 255) / 256;

    const float* feat_in[3] = {(const float*)d_in[0], (const float*)d_in[1], (const float*)d_in[2]};
    const float* W     = (const float*)d_in[3];
    const float* gamma = (const float*)d_in[5];
    const float* beta  = (const float*)d_in[6];
    float* ws  = (float*)d_ws;
    float* out = (float*)d_out;

    int ns_base[9], nd_base[9];
    {
        int s = 0, d = 0;
        for (int r = 0; r < 9; ++r) {
            ns_base[r] = s; s += NT[RSRC[r]];
            nd_base[r] = d; d += NT[RDST[r]];
        }
    }

    // workspace layout (float units; bf16 buffers use half-count)
    const size_t H_A    = 0;                        // 100000*128 bf16
    const size_t H_B    = H_A + 6400000;            // 150000*128 bf16
    const size_t H_G    = H_B + 9600000;            // 2000*128 bf16
    const size_t MBUF   = H_G + 128000;             // small-path m buffer (bf16)
    const size_t OUT    = MBUF + 9600000;           // 150000*128 fp32
    const size_t WT     = OUT + 19200000;           // 18*128*128 bf16
    const size_t STATS  = WT + 147456;              // 18*256 fp32
    const size_t NS     = STATS + 4608;             // 756000
    const size_t ND     = NS + 756000;              // 756000
    const size_t OFFS   = ND + 756000;              // 756000 ints
    const size_t SORTED = OFFS + 756000;            // 1352000 ints
    const size_t BSUM   = SORTED + 1352000;         // scan blocks

    ushort* h_feat[3] = {(ushort*)(ws + H_A), (ushort*)(ws + H_B), (ushort*)(ws + H_G)};
    float* out_feat[3] = {out, out + 12800000, out + 32000000};
    ushort* mbuf   = (ushort*)(ws + MBUF);
    float*  obuf   = ws + OUT;
    ushort* wt     = (ushort*)(ws + WT);
    float*  stats0 = ws + STATS;
    float*  ns_blk = ws + NS;
    float*  nd_blk = ws + ND;
    int*    offs   = (int*)(ws + OFFS);
    int*    sorted = (int*)(ws + SORTED);
    int*    bsum   = (int*)(ws + BSUM);

    // zero stats + degree counters (contiguous)
    hipMemsetAsync(ws + STATS, 0, (4608 + 2 * 756000) * sizeof(float), stream);

    for (int r = 0; r < 9; ++r) {
        const int* src = (const int*)d_in[7 + 2 * r];
        const int* dst = (const int*)d_in[8 + 2 * r];
        k_count<<<(RE[r] + 255) / 256, 256, 0, stream>>>(
            src, dst, RE[r], ns_blk + ns_base[r], nd_blk + nd_base[r]);
    }
    k_scan1<<<NB, 256, 0, stream>>>(nd_blk, offs, bsum, TOT_N);
    k_scan2<<<1, 1024, 0, stream>>>(bsum, NB);
    k_scan3<<<NB, 256, 0, stream>>>(offs, bsum, TOT_N);
    for (int r = 0; r < 9; ++r) {
        const int* src = (const int*)d_in[7 + 2 * r];
        const int* dst = (const int*)d_in[8 + 2 * r];
        k_fill<<<(RE[r] + 255) / 256, 256, 0, stream>>>(
            src, dst, RE[r], offs + nd_base[r], sorted);
    }
    k_rsqrt<<<(2 * TOT_N + 255) / 256, 256, 0, stream>>>(ns_blk, 2 * TOT_N);
    k_prepw<<<(18 * 16384 + 255) / 256, 256, 0, stream>>>(W, wt);

    for (int l = 0; l < 2; ++l) {
        bool touched[3] = {false, false, false};
        for (int r = 0; r < 9; ++r) {
            int st = RSRC[r], dt = RDST[r];
            int n_dst = NT[dt];

            float* stats = stats0 + (size_t)(l * 9 + r) * 256;
            const ushort* wfr = wt + (size_t)(l * 9 + r) * 16384;

            if (dt == 2) {
                // small-n_dst path: parallel gather (32 thr/row) + separate GEMM
                if (l == 0)
                    k_gather<float><<<((size_t)n_dst * 32 + 255) / 256, 256, 0, stream>>>(
                        feat_in[st], ns_blk + ns_base[r], nd_blk + nd_base[r],
                        offs, nd_base[r], sorted, n_dst, mbuf);
                else
                    k_gather<ushort><<<((size_t)n_dst * 32 + 255) / 256, 256, 0, stream>>>(
                        h_feat[st], ns_blk + ns_base[r], nd_blk + nd_base[r],
                        offs, nd_base[r], sorted, n_dst, mbuf);
                k_gemm_mfma<<<(n_dst + 127) / 128, 256, 0, stream>>>(
                    mbuf, wfr, n_dst, obuf, stats);
            } else {
                int nblk = (n_dst + 127) / 128;
                if (l == 0)
                    k_fused2<float><<<nblk, 512, 0, stream>>>(
                        feat_in[st], ns_blk + ns_base[r], nd_blk + nd_base[r],
                        offs, nd_base[r], sorted, wfr, n_dst, obuf, stats);
                else
                    k_fused2<ushort><<<nblk, 512, 0, stream>>>(
                        h_feat[st], ns_blk + ns_base[r], nd_blk + nd_base[r],
                        offs, nd_base[r], sorted, wfr, n_dst, obuf, stats);
            }

            int total4 = n_dst * 32;
            int ngrid = (total4 + 255) / 256;
            if (ngrid > 2048) ngrid = 2048;
            const float* g = gamma + (size_t)(l * 9 + r) * D;
            const float* b = beta  + (size_t)(l * 9 + r) * D;
            if (l == 0) {
                int mode = touched[dt] ? 1 : 0;
                k_norm_bf<<<ngrid, 256, 0, stream>>>(
                    (const float4*)obuf, stats, g, b, 1.0f / (float)n_dst,
                    total4, h_feat[dt], mode);
            } else {
                int mode = touched[dt] ? 1 : 2;
                k_norm<<<ngrid, 256, 0, stream>>>(
                    (const float4*)obuf, stats, g, b, 1.0f / (float)n_dst,
                    total4, (float4*)out_feat[dt], (const float4*)feat_in[dt], mode);
            }
            touched[dt] = true;
        }
    }
}

// Round 7
// 1642.149 us; speedup vs baseline: 2.0456x; 1.0574x over previous
//
#include <hip/hip_runtime.h>
#include <cstdint>

#define D 128

typedef __attribute__((ext_vector_type(8))) short short8;
typedef __attribute__((ext_vector_type(4))) float f32x4;

__device__ inline ushort f2bf(float f) {
    uint u = __float_as_uint(f);
    uint r = (u + 0x7fffu + ((u >> 16) & 1u)) >> 16;
    return (ushort)r;
}
__device__ inline float bf2f(ushort u) { return __uint_as_float(((uint)u) << 16); }

// ---------------------------------------------------------------- degree / CSR build

__global__ void k_count(const int* __restrict__ src, const int* __restrict__ dst,
                        int E, float* __restrict__ degs, float* __restrict__ degd) {
    int i = blockIdx.x * blockDim.x + threadIdx.x;
    if (i < E) {
        atomicAdd(&degs[src[i]], 1.0f);
        atomicAdd(&degd[dst[i]], 1.0f);
    }
}

__global__ void k_rsqrt(float* __restrict__ p, int n) {
    int i = blockIdx.x * blockDim.x + threadIdx.x;
    if (i < n) {
        float d = p[i];
        p[i] = d > 0.0f ? rsqrtf(d) : 0.0f;
    }
}

__global__ void k_scan1(const float* __restrict__ cnt, int* __restrict__ off,
                        int* __restrict__ bsum, int n) {
    __shared__ int s[256];
    int t = threadIdx.x, i = blockIdx.x * 256 + t;
    int v = (i < n) ? (int)cnt[i] : 0;
    int acc = v;
    s[t] = acc; __syncthreads();
    for (int d = 1; d < 256; d <<= 1) {
        int add = (t >= d) ? s[t - d] : 0;
        __syncthreads();
        acc += add; s[t] = acc; __syncthreads();
    }
    if (i < n) off[i] = acc - v;
    if (t == 255) bsum[blockIdx.x] = acc;
}

__global__ __launch_bounds__(1024) void k_scan2(int* __restrict__ bsum, int nb) {
    __shared__ int s[1024];
    int t = threadIdx.x;
    int i0 = t * 3;
    int v0 = (i0     < nb) ? bsum[i0]     : 0;
    int v1 = (i0 + 1 < nb) ? bsum[i0 + 1] : 0;
    int v2 = (i0 + 2 < nb) ? bsum[i0 + 2] : 0;
    int tot = v0 + v1 + v2;
    int acc = tot;
    s[t] = acc; __syncthreads();
    for (int d = 1; d < 1024; d <<= 1) {
        int add = (t >= d) ? s[t - d] : 0;
        __syncthreads();
        acc += add; s[t] = acc; __syncthreads();
    }
    int base = acc - tot;
    if (i0     < nb) bsum[i0]     = base;
    if (i0 + 1 < nb) bsum[i0 + 1] = base + v0;
    if (i0 + 2 < nb) bsum[i0 + 2] = base + v0 + v1;
}

__global__ void k_scan3(int* __restrict__ off, const int* __restrict__ bsum, int n) {
    int i = blockIdx.x * 256 + threadIdx.x;
    if (i < n) off[i] += bsum[blockIdx.x];
}

__global__ void k_fill(const int* __restrict__ src, const int* __restrict__ dst,
                       int E, int* __restrict__ offs, int* __restrict__ sorted) {
    int e = blockIdx.x * blockDim.x + threadIdx.x;
    if (e < E) {
        int pos = atomicAdd(&offs[dst[e]], 1);
        sorted[pos] = src[e];
    }
}

// W[18][128k][128n] fp32 -> Wf fragment-major bf16:
// Wf[r][c][kbi][lane][e]  (c=col-tile 0..7, kbi=k-block 0..3, lane=lm+16*lg, e=0..7)
//   holds W[k = kbi*32 + lg*8 + e][ncol = c*16 + lm]
__global__ void k_prepw(const float* __restrict__ W, ushort* __restrict__ Wf) {
    int i = blockIdx.x * 256 + threadIdx.x;
    if (i < 18 * 16384) {
        int r = i >> 14, j = i & 16383;
        int e = j & 7, lane = (j >> 3) & 63, kbi = (j >> 9) & 3, c = j >> 11;
        int lm = lane & 15, lg = lane >> 4;
        int k = kbi * 32 + lg * 8 + e, ncol = c * 16 + lm;
        Wf[i] = f2bf(W[(r << 14) + (k << 7) + ncol]);
    }
}

// ---------------------------------------------------------------- gather helpers

__device__ inline float4 loadx(const float* x, size_t idx) { return *(const float4*)(x + idx); }
__device__ inline float4 loadx(const ushort* x, size_t idx) {
    ushort4 u = *(const ushort4*)(x + idx);
    float4 v;
    v.x = bf2f(u.x); v.y = bf2f(u.y); v.z = bf2f(u.z); v.w = bf2f(u.w);
    return v;
}

// separate gather (small-n_dst path): 32 threads per row, one row per thread-group
template <typename XT>
__global__ void k_gather(const XT* __restrict__ x, const float* __restrict__ ns,
                         const float* __restrict__ nd,
                         const int* __restrict__ OFFS, int gdbase,
                         const int* __restrict__ sorted, int n_dst,
                         ushort* __restrict__ m) {
    int gid = blockIdx.x * blockDim.x + threadIdx.x;
    int row = gid >> 5;
    if (row >= n_dst) return;
    int c4 = (gid & 31) * 4;
    int gd = gdbase + row;
    int beg = (gd == 0) ? 0 : OFFS[gd - 1];
    int end = OFFS[gd];
    float4 acc = {0.f, 0.f, 0.f, 0.f};
    for (int j = beg; j < end; ++j) {
        int s = sorted[j];
        float w = ns[s];
        float4 v = loadx(x, ((size_t)s << 7) + c4);
        acc.x += v.x * w; acc.y += v.y * w; acc.z += v.z * w; acc.w += v.w * w;
    }
    float sc = nd[row];
    ushort4 o;
    o.x = f2bf(acc.x * sc); o.y = f2bf(acc.y * sc);
    o.z = f2bf(acc.z * sc); o.w = f2bf(acc.w * sc);
    *(ushort4*)(m + ((size_t)row << 7) + c4) = o;
}

// separate GEMM (small-n_dst path): 4 waves, each owns an independent 32-row tile
__global__ __launch_bounds__(256) void k_gemm_mfma(
    const ushort* __restrict__ mb, const ushort* __restrict__ Wf,
    int n, float* __restrict__ outp, float* __restrict__ stats) {
    __shared__ ushort Wl[16384];
    __shared__ float Sl[256];
    int t = threadIdx.x;
    int w = t >> 6, lane = t & 63, lm = lane & 15, lg = lane >> 4;
    Sl[t] = 0.0f;

    #pragma unroll
    for (int i = 0; i < 8; ++i) {
        int ci = t + 256 * i;
        *(short8*)&Wl[ci * 8] = *(const short8*)&Wf[ci * 8];
    }
    __syncthreads();

    int R = (blockIdx.x * 4 + w) * 32;
    float rs1[8] = {0.f, 0.f, 0.f, 0.f, 0.f, 0.f, 0.f, 0.f};
    float rs2[8] = {0.f, 0.f, 0.f, 0.f, 0.f, 0.f, 0.f, 0.f};

    if (R < n) {
        f32x4 acc[2][8] = {};
        int r0 = R + lm, r1 = R + 16 + lm;
        const ushort* a0p = mb + (((size_t)r0) << 7) + lg * 8;
        const ushort* a1p = mb + (((size_t)r1) << 7) + lg * 8;
        bool v0 = r0 < n, v1 = r1 < n;
        #pragma unroll
        for (int kbi = 0; kbi < 4; ++kbi) {
            short8 a0 = {}, a1 = {};
            if (v0) a0 = *(const short8*)(a0p + kbi * 32);
            if (v1) a1 = *(const short8*)(a1p + kbi * 32);
            #pragma unroll
            for (int c = 0; c < 8; ++c) {
                short8 b = *(short8*)&Wl[((c * 4 + kbi) * 64 + lane) * 8];
                acc[0][c] = __builtin_amdgcn_mfma_f32_16x16x32_bf16(a0, b, acc[0][c], 0, 0, 0);
                acc[1][c] = __builtin_amdgcn_mfma_f32_16x16x32_bf16(a1, b, acc[1][c], 0, 0, 0);
            }
        }
        #pragma unroll
        for (int m = 0; m < 2; ++m) {
            int rowb = R + m * 16 + lg * 4;
            #pragma unroll
            for (int c = 0; c < 8; ++c) {
                f32x4 v = acc[m][c];
                rs1[c] += v[0] + v[1] + v[2] + v[3];
                rs2[c] += v[0] * v[0] + v[1] * v[1] + v[2] * v[2] + v[3] * v[3];
                #pragma unroll
                for (int i2 = 0; i2 < 4; ++i2) {
                    int row = rowb + i2;
                    if (row < n)
                        outp[((size_t)row << 7) + c * 16 + lm] = v[i2];
                }
            }
        }
    }

    #pragma unroll
    for (int c = 0; c < 8; ++c) {
        float s1 = rs1[c], s2 = rs2[c];
        s1 += __shfl_xor(s1, 16); s1 += __shfl_xor(s1, 32);
        s2 += __shfl_xor(s2, 16); s2 += __shfl_xor(s2, 32);
        if (lg == 0) {
            atomicAdd(&Sl[c * 16 + lm], s1);
            atomicAdd(&Sl[128 + c * 16 + lm], s2);
        }
    }
    __syncthreads();
    atomicAdd(&stats[t], Sl[t]);
}

// ---------------------------------------------------------------- fused gather + MFMA (big-n_dst path)

// 512 threads = 8 waves per block, 128 rows/block. Each wave owns 16
// independent rows; lane (lm,lg) gathers row R+lm, channel octets
// (kbi*4+lg)*8 (kbi=0..3) -- exactly its MFMA A-fragment slots, accumulated
// in registers and converted to bf16 in-register. LDS holds only W (32 KB):
// 4 blocks/CU x 8 waves = 32 waves/CU (full wave cap).
template <typename XT>
__global__ __launch_bounds__(512) void k_fused2(
    const XT* __restrict__ x, const float* __restrict__ ns,
    const float* __restrict__ nd,
    const int* __restrict__ OFFS, int gdbase,
    const int* __restrict__ sorted,
    const ushort* __restrict__ Wf,
    int n, float* __restrict__ outp, float* __restrict__ stats) {
    __shared__ ushort Wl[16384];
    __shared__ float Sl[256];
    int t = threadIdx.x;
    if (t < 256) Sl[t] = 0.0f;

    #pragma unroll
    for (int i = 0; i < 4; ++i) {
        int ci = t + 512 * i;
        *(short8*)&Wl[ci * 8] = *(const short8*)&Wf[ci * 8];
    }

    int w = t >> 6, lane = t & 63, lm = lane & 15, lg = lane >> 4;
    int R = blockIdx.x * 128 + w * 16;
    int row = R + lm;

    float a[4][8] = {};
    float scale = 0.0f;
    if (row < n) {
        int gd = gdbase + row;
        int beg = (gd == 0) ? 0 : OFFS[gd - 1];
        int end = OFFS[gd];
        for (int j = beg; j < end; ++j) {
            int s = sorted[j];
            float wgt = ns[s];
            size_t xb = (size_t)s << 7;
            #pragma unroll
            for (int kbi = 0; kbi < 4; ++kbi) {
                int cb = (kbi * 4 + lg) * 8;
                float4 u0 = loadx(x, xb + cb);
                float4 u1 = loadx(x, xb + cb + 4);
                a[kbi][0] += u0.x * wgt; a[kbi][1] += u0.y * wgt;
                a[kbi][2] += u0.z * wgt; a[kbi][3] += u0.w * wgt;
                a[kbi][4] += u1.x * wgt; a[kbi][5] += u1.y * wgt;
                a[kbi][6] += u1.z * wgt; a[kbi][7] += u1.w * wgt;
            }
        }
        scale = nd[row];
    }

    // convert to bf16 A-fragments in-register
    short8 af[4];
    #pragma unroll
    for (int kbi = 0; kbi < 4; ++kbi) {
        #pragma unroll
        for (int e = 0; e < 8; ++e)
            af[kbi][e] = (short)f2bf(a[kbi][e] * scale);
    }

    __syncthreads();   // Wl ready

    float rs1[8] = {0.f, 0.f, 0.f, 0.f, 0.f, 0.f, 0.f, 0.f};
    float rs2[8] = {0.f, 0.f, 0.f, 0.f, 0.f, 0.f, 0.f, 0.f};

    if (R < n) {
        f32x4 acc[8] = {};
        #pragma unroll
        for (int kbi = 0; kbi < 4; ++kbi) {
            #pragma unroll
            for (int c = 0; c < 8; ++c) {
                short8 b = *(short8*)&Wl[((c * 4 + kbi) * 64 + lane) * 8];
                acc[c] = __builtin_amdgcn_mfma_f32_16x16x32_bf16(af[kbi], b, acc[c], 0, 0, 0);
            }
        }
        int rowb = R + lg * 4;
        #pragma unroll
        for (int c = 0; c < 8; ++c) {
            f32x4 v = acc[c];
            rs1[c] += v[0] + v[1] + v[2] + v[3];
            rs2[c] += v[0] * v[0] + v[1] * v[1] + v[2] * v[2] + v[3] * v[3];
            #pragma unroll
            for (int i2 = 0; i2 < 4; ++i2) {
                int crow = rowb + i2;
                if (crow < n)
                    outp[((size_t)crow << 7) + c * 16 + lm] = v[i2];
            }
        }
    }

    #pragma unroll
    for (int c = 0; c < 8; ++c) {
        float s1 = rs1[c], s2 = rs2[c];
        s1 += __shfl_xor(s1, 16); s1 += __shfl_xor(s1, 32);
        s2 += __shfl_xor(s2, 16); s2 += __shfl_xor(s2, 32);
        if (lg == 0) {
            atomicAdd(&Sl[c * 16 + lm], s1);
            atomicAdd(&Sl[128 + c * 16 + lm], s2);
        }
    }
    __syncthreads();
    if (t < 256) atomicAdd(&stats[t], Sl[t]);
}

// ---------------------------------------------------------------- combined 3-relation BN normalize

// l0: dst = bf16( aff0(o0) + aff1(o1) + aff2(o2) )
__global__ void k_norm3_bf(const float4* __restrict__ o0, const float4* __restrict__ o1,
                           const float4* __restrict__ o2,
                           const float* __restrict__ st0, const float* __restrict__ st1,
                           const float* __restrict__ st2,
                           const float* __restrict__ g0, const float* __restrict__ g1,
                           const float* __restrict__ g2,
                           const float* __restrict__ b0, const float* __restrict__ b1,
                           const float* __restrict__ b2,
                           float inv_n, int total4, ushort* __restrict__ dst) {
    __shared__ float sc[3][128], sh[3][128];
    int t = threadIdx.x;
    if (t < 128) {
        float mu0 = st0[t] * inv_n, va0 = st0[128 + t] * inv_n - mu0 * mu0;
        float s0 = g0[t] * rsqrtf(va0 + 1e-5f); sc[0][t] = s0; sh[0][t] = b0[t] - mu0 * s0;
        float mu1 = st1[t] * inv_n, va1 = st1[128 + t] * inv_n - mu1 * mu1;
        float s1 = g1[t] * rsqrtf(va1 + 1e-5f); sc[1][t] = s1; sh[1][t] = b1[t] - mu1 * s1;
        float mu2 = st2[t] * inv_n, va2 = st2[128 + t] * inv_n - mu2 * mu2;
        float s2 = g2[t] * rsqrtf(va2 + 1e-5f); sc[2][t] = s2; sh[2][t] = b2[t] - mu2 * s2;
    }
    __syncthreads();
    for (int i = blockIdx.x * blockDim.x + t; i < total4; i += gridDim.x * blockDim.x) {
        int c4 = (i & 31) * 4;
        float4 v0 = o0[i], v1 = o1[i], v2 = o2[i];
        float4 r;
        r.x = (v0.x * sc[0][c4+0] + sh[0][c4+0]) + (v1.x * sc[1][c4+0] + sh[1][c4+0]) + (v2.x * sc[2][c4+0] + sh[2][c4+0]);
        r.y = (v0.y * sc[0][c4+1] + sh[0][c4+1]) + (v1.y * sc[1][c4+1] + sh[1][c4+1]) + (v2.y * sc[2][c4+1] + sh[2][c4+1]);
        r.z = (v0.z * sc[0][c4+2] + sh[0][c4+2]) + (v1.z * sc[1][c4+2] + sh[1][c4+2]) + (v2.z * sc[2][c4+2] + sh[2][c4+2]);
        r.w = (v0.w * sc[0][c4+3] + sh[0][c4+3]) + (v1.w * sc[1][c4+3] + sh[1][c4+3]) + (v2.w * sc[2][c4+3] + sh[2][c4+3]);
        ushort4 o;
        o.x = f2bf(r.x); o.y = f2bf(r.y); o.z = f2bf(r.z); o.w = f2bf(r.w);
        *(ushort4*)(dst + (size_t)i * 4) = o;
    }
}

// l1: dst = aff0(o0) + aff1(o1) + aff2(o2) + resid  (fp32)
__global__ void k_norm3_f32(const float4* __restrict__ o0, const float4* __restrict__ o1,
                            const float4* __restrict__ o2,
                            const float* __restrict__ st0, const float* __restrict__ st1,
                            const float* __restrict__ st2,
                            const float* __restrict__ g0, const float* __restrict__ g1,
                            const float* __restrict__ g2,
                            const float* __restrict__ b0, const float* __restrict__ b1,
                            const float* __restrict__ b2,
                            float inv_n, int total4, float4* __restrict__ dst,
                            const float4* __restrict__ resid4) {
    __shared__ float sc[3][128], sh[3][128];
    int t = threadIdx.x;
    if (t < 128) {
        float mu0 = st0[t] * inv_n, va0 = st0[128 + t] * inv_n - mu0 * mu0;
        float s0 = g0[t] * rsqrtf(va0 + 1e-5f); sc[0][t] = s0; sh[0][t] = b0[t] - mu0 * s0;
        float mu1 = st1[t] * inv_n, va1 = st1[128 + t] * inv_n - mu1 * mu1;
        float s1 = g1[t] * rsqrtf(va1 + 1e-5f); sc[1][t] = s1; sh[1][t] = b1[t] - mu1 * s1;
        float mu2 = st2[t] * inv_n, va2 = st2[128 + t] * inv_n - mu2 * mu2;
        float s2 = g2[t] * rsqrtf(va2 + 1e-5f); sc[2][t] = s2; sh[2][t] = b2[t] - mu2 * s2;
    }
    __syncthreads();
    for (int i = blockIdx.x * blockDim.x + t; i < total4; i += gridDim.x * blockDim.x) {
        int c4 = (i & 31) * 4;
        float4 v0 = o0[i], v1 = o1[i], v2 = o2[i], d = resid4[i];
        float4 r;
        r.x = (v0.x * sc[0][c4+0] + sh[0][c4+0]) + (v1.x * sc[1][c4+0] + sh[1][c4+0]) + (v2.x * sc[2][c4+0] + sh[2][c4+0]) + d.x;
        r.y = (v0.y * sc[0][c4+1] + sh[0][c4+1]) + (v1.y * sc[1][c4+1] + sh[1][c4+1]) + (v2.y * sc[2][c4+1] + sh[2][c4+1]) + d.y;
        r.z = (v0.z * sc[0][c4+2] + sh[0][c4+2]) + (v1.z * sc[1][c4+2] + sh[1][c4+2]) + (v2.z * sc[2][c4+2] + sh[2][c4+2]) + d.z;
        r.w = (v0.w * sc[0][c4+3] + sh[0][c4+3]) + (v1.w * sc[1][c4+3] + sh[1][c4+3]) + (v2.w * sc[2][c4+3] + sh[2][c4+3]) + d.w;
        dst[i] = r;
    }
}

// ---------------------------------------------------------------- launch

extern "C" void kernel_launch(void* const* d_in, const int* in_sizes, int n_in,
                              void* d_out, int out_size, void* d_ws, size_t ws_size,
                              hipStream_t stream) {
    static const int NT[3]   = {100000, 150000, 2000};
    static const int RE[9]   = {300000, 300000, 100000, 100000, 150000, 150000, 100000, 150000, 2000};
    static const int RSRC[9] = {0, 1, 0, 2, 1, 2, 0, 1, 2};
    static const int RDST[9] = {1, 0, 2, 0, 2, 1, 0, 1, 2};
    // relations per dst type, ascending r (matches reference accumulation order)
    static const int DREL[3][3] = {{1, 3, 6}, {0, 5, 7}, {2, 4, 8}};
    const int TOT_N = 756000;
    const int NB = (TOT_N + 255) / 256;

    const float* feat_in[3] = {(const float*)d_in[0], (const float*)d_in[1], (const float*)d_in[2]};
    const float* W     = (const float*)d_in[3];
    const float* gamma = (const float*)d_in[5];
    const float* beta  = (const float*)d_in[6];
    float* ws  = (float*)d_ws;
    float* out = (float*)d_out;

    int ns_base[9], nd_base[9];
    {
        int s = 0, d = 0;
        for (int r = 0; r < 9; ++r) {
            ns_base[r] = s; s += NT[RSRC[r]];
            nd_base[r] = d; d += NT[RDST[r]];
        }
    }

    // workspace layout (float units; bf16 buffers use half-count)
    const size_t H_A    = 0;                        // 100000*128 bf16
    const size_t H_B    = H_A + 6400000;            // 150000*128 bf16
    const size_t H_G    = H_B + 9600000;            // 2000*128 bf16
    const size_t MBUF   = H_G + 128000;             // small-path m buffer (bf16)
    const size_t OUT    = MBUF + 9600000;           // 3 slots x 150000*128 fp32
    const size_t WT     = OUT + 3 * 19200000;       // 18*128*128 bf16
    const size_t STATS  = WT + 147456;              // 18*256 fp32
    const size_t NS     = STATS + 4608;             // 756000
    const size_t ND     = NS + 756000;              // 756000
    const size_t OFFS   = ND + 756000;              // 756000 ints
    const size_t SORTED = OFFS + 756000;            // 1352000 ints
    const size_t BSUM   = SORTED + 1352000;         // scan blocks

    ushort* h_feat[3] = {(ushort*)(ws + H_A), (ushort*)(ws + H_B), (ushort*)(ws + H_G)};
    float* out_feat[3] = {out, out + 12800000, out + 32000000};
    ushort* mbuf   = (ushort*)(ws + MBUF);
    float*  obuf[3] = {ws + OUT, ws + OUT + 19200000, ws + OUT + 38400000};
    ushort* wt     = (ushort*)(ws + WT);
    float*  stats0 = ws + STATS;
    float*  ns_blk = ws + NS;
    float*  nd_blk = ws + ND;
    int*    offs   = (int*)(ws + OFFS);
    int*    sorted = (int*)(ws + SORTED);
    int*    bsum   = (int*)(ws + BSUM);

    // zero stats + degree counters (contiguous)
    hipMemsetAsync(ws + STATS, 0, (4608 + 2 * 756000) * sizeof(float), stream);

    for (int r = 0; r < 9; ++r) {
        const int* src = (const int*)d_in[7 + 2 * r];
        const int* dst = (const int*)d_in[8 + 2 * r];
        k_count<<<(RE[r] + 255) / 256, 256, 0, stream>>>(
            src, dst, RE[r], ns_blk + ns_base[r], nd_blk + nd_base[r]);
    }
    k_scan1<<<NB, 256, 0, stream>>>(nd_blk, offs, bsum, TOT_N);
    k_scan2<<<1, 1024, 0, stream>>>(bsum, NB);
    k_scan3<<<NB, 256, 0, stream>>>(offs, bsum, TOT_N);
    for (int r = 0; r < 9; ++r) {
        const int* src = (const int*)d_in[7 + 2 * r];
        const int* dst = (const int*)d_in[8 + 2 * r];
        k_fill<<<(RE[r] + 255) / 256, 256, 0, stream>>>(
            src, dst, RE[r], offs + nd_base[r], sorted);
    }
    k_rsqrt<<<(2 * TOT_N + 255) / 256, 256, 0, stream>>>(ns_blk, 2 * TOT_N);
    k_prepw<<<(18 * 16384 + 255) / 256, 256, 0, stream>>>(W, wt);

    for (int l = 0; l < 2; ++l) {
        for (int dt = 0; dt < 3; ++dt) {
            int n_dst = NT[dt];
            const int* rl = DREL[dt];

            for (int s = 0; s < 3; ++s) {
                int r = rl[s];
                int st = RSRC[r];
                float* stats = stats0 + (size_t)(l * 9 + r) * 256;
                const ushort* wfr = wt + (size_t)(l * 9 + r) * 16384;

                if (dt == 2) {
                    // small-n_dst path: parallel gather (32 thr/row) + separate GEMM
                    if (l == 0)
                        k_gather<float><<<((size_t)n_dst * 32 + 255) / 256, 256, 0, stream>>>(
                            feat_in[st], ns_blk + ns_base[r], nd_blk + nd_base[r],
                            offs, nd_base[r], sorted, n_dst, mbuf);
                    else
                        k_gather<ushort><<<((size_t)n_dst * 32 + 255) / 256, 256, 0, stream>>>(
                            h_feat[st], ns_blk + ns_base[r], nd_blk + nd_base[r],
                            offs, nd_base[r], sorted, n_dst, mbuf);
                    k_gemm_mfma<<<(n_dst + 127) / 128, 256, 0, stream>>>(
                        mbuf, wfr, n_dst, obuf[s], stats);
                } else {
                    int nblk = (n_dst + 127) / 128;
                    if (l == 0)
                        k_fused2<float><<<nblk, 512, 0, stream>>>(
                            feat_in[st], ns_blk + ns_base[r], nd_blk + nd_base[r],
                            offs, nd_base[r], sorted, wfr, n_dst, obuf[s], stats);
                    else
                        k_fused2<ushort><<<nblk, 512, 0, stream>>>(
                            h_feat[st], ns_blk + ns_base[r], nd_blk + nd_base[r],
                            offs, nd_base[r], sorted, wfr, n_dst, obuf[s], stats);
                }
            }

            // one combined norm for this dst
            int r0 = rl[0], r1 = rl[1], r2 = rl[2];
            const float* st0 = stats0 + (size_t)(l * 9 + r0) * 256;
            const float* st1 = stats0 + (size_t)(l * 9 + r1) * 256;
            const float* st2 = stats0 + (size_t)(l * 9 + r2) * 256;
            const float* g0 = gamma + (size_t)(l * 9 + r0) * D;
            const float* g1 = gamma + (size_t)(l * 9 + r1) * D;
            const float* g2 = gamma + (size_t)(l * 9 + r2) * D;
            const float* b0 = beta + (size_t)(l * 9 + r0) * D;
            const float* b1 = beta + (size_t)(l * 9 + r1) * D;
            const float* b2 = beta + (size_t)(l * 9 + r2) * D;
            int total4 = n_dst * 32;
            int ngrid = (total4 + 255) / 256;
            if (ngrid > 2048) ngrid = 2048;
            float inv_n = 1.0f / (float)n_dst;

            if (l == 0)
                k_norm3_bf<<<ngrid, 256, 0, stream>>>(
                    (const float4*)obuf[0], (const float4*)obuf[1], (const float4*)obuf[2],
                    st0, st1, st2, g0, g1, g2, b0, b1, b2,
                    inv_n, total4, h_feat[dt]);
            else
                k_norm3_f32<<<ngrid, 256, 0, stream>>>(
                    (const float4*)obuf[0], (const float4*)obuf[1], (const float4*)obuf[2],
                    st0, st1, st2, g0, g1, g2, b0, b1, b2,
                    inv_n, total4, (float4*)out_feat[dt], (const float4*)feat_in[dt]);
        }
    }
}

// Round 8
// 1470.086 us; speedup vs baseline: 2.2850x; 1.1170x over previous
//
#include <hip/hip_runtime.h>
#include <cstdint>

#define D 128

typedef __attribute__((ext_vector_type(8))) short short8;
typedef __attribute__((ext_vector_type(4))) float f32x4;

__device__ inline ushort f2bf(float f) {
    uint u = __float_as_uint(f);
    uint r = (u + 0x7fffu + ((u >> 16) & 1u)) >> 16;
    return (ushort)r;
}
__device__ inline float bf2f(ushort u) { return __uint_as_float(((uint)u) << 16); }

// ---------------------------------------------------------------- degree / CSR build

__global__ void k_count(const int* __restrict__ src, const int* __restrict__ dst,
                        int E, float* __restrict__ degs, float* __restrict__ degd) {
    int i = blockIdx.x * blockDim.x + threadIdx.x;
    if (i < E) {
        atomicAdd(&degs[src[i]], 1.0f);
        atomicAdd(&degd[dst[i]], 1.0f);
    }
}

__global__ void k_rsqrt(float* __restrict__ p, int n) {
    int i = blockIdx.x * blockDim.x + threadIdx.x;
    if (i < n) {
        float d = p[i];
        p[i] = d > 0.0f ? rsqrtf(d) : 0.0f;
    }
}

__global__ void k_scan1(const float* __restrict__ cnt, int* __restrict__ off,
                        int* __restrict__ bsum, int n) {
    __shared__ int s[256];
    int t = threadIdx.x, i = blockIdx.x * 256 + t;
    int v = (i < n) ? (int)cnt[i] : 0;
    int acc = v;
    s[t] = acc; __syncthreads();
    for (int d = 1; d < 256; d <<= 1) {
        int add = (t >= d) ? s[t - d] : 0;
        __syncthreads();
        acc += add; s[t] = acc; __syncthreads();
    }
    if (i < n) off[i] = acc - v;
    if (t == 255) bsum[blockIdx.x] = acc;
}

__global__ __launch_bounds__(1024) void k_scan2(int* __restrict__ bsum, int nb) {
    __shared__ int s[1024];
    int t = threadIdx.x;
    int i0 = t * 3;
    int v0 = (i0     < nb) ? bsum[i0]     : 0;
    int v1 = (i0 + 1 < nb) ? bsum[i0 + 1] : 0;
    int v2 = (i0 + 2 < nb) ? bsum[i0 + 2] : 0;
    int tot = v0 + v1 + v2;
    int acc = tot;
    s[t] = acc; __syncthreads();
    for (int d = 1; d < 1024; d <<= 1) {
        int add = (t >= d) ? s[t - d] : 0;
        __syncthreads();
        acc += add; s[t] = acc; __syncthreads();
    }
    int base = acc - tot;
    if (i0     < nb) bsum[i0]     = base;
    if (i0 + 1 < nb) bsum[i0 + 1] = base + v0;
    if (i0 + 2 < nb) bsum[i0 + 2] = base + v0 + v1;
}

__global__ void k_scan3(int* __restrict__ off, const int* __restrict__ bsum, int n) {
    int i = blockIdx.x * 256 + threadIdx.x;
    if (i < n) off[i] += bsum[blockIdx.x];
}

__global__ void k_fill(const int* __restrict__ src, const int* __restrict__ dst,
                       int E, int* __restrict__ offs, int* __restrict__ sorted) {
    int e = blockIdx.x * blockDim.x + threadIdx.x;
    if (e < E) {
        int pos = atomicAdd(&offs[dst[e]], 1);
        sorted[pos] = src[e];
    }
}

// W[18][128k][128n] fp32 -> Wf fragment-major bf16:
// Wf[r][c][kbi][lane][e]  (c=col-tile 0..7, kbi=k-block 0..3, lane=lm+16*lg, e=0..7)
//   holds W[k = kbi*32 + lg*8 + e][ncol = c*16 + lm]
__global__ void k_prepw(const float* __restrict__ W, ushort* __restrict__ Wf) {
    int i = blockIdx.x * 256 + threadIdx.x;
    if (i < 18 * 16384) {
        int r = i >> 14, j = i & 16383;
        int e = j & 7, lane = (j >> 3) & 63, kbi = (j >> 9) & 3, c = j >> 11;
        int lm = lane & 15, lg = lane >> 4;
        int k = kbi * 32 + lg * 8 + e, ncol = c * 16 + lm;
        Wf[i] = f2bf(W[(r << 14) + (k << 7) + ncol]);
    }
}

// ---------------------------------------------------------------- gather helpers

__device__ inline float4 loadx(const float* x, size_t idx) { return *(const float4*)(x + idx); }
__device__ inline float4 loadx(const ushort* x, size_t idx) {
    ushort4 u = *(const ushort4*)(x + idx);
    float4 v;
    v.x = bf2f(u.x); v.y = bf2f(u.y); v.z = bf2f(u.z); v.w = bf2f(u.w);
    return v;
}

// small-n_dst, high-degree path: ONE BLOCK PER ROW.
// 8 edge-groups x 32 channel-quads; each thread strides the edge list by 8,
// partials reduced through LDS. Kills the serial 50-75-edge latency chain.
template <typename XT>
__global__ __launch_bounds__(256) void k_gather_row(
    const XT* __restrict__ x, const float* __restrict__ ns,
    const float* __restrict__ nd,
    const int* __restrict__ OFFS, int gdbase,
    const int* __restrict__ sorted, int n_dst,
    ushort* __restrict__ m) {
    __shared__ float4 part[8][32];
    int row = blockIdx.x;
    if (row >= n_dst) return;
    int t = threadIdx.x;
    int g = t >> 5, q = t & 31;
    int c4 = q * 4;
    int gd = gdbase + row;
    int beg = (gd == 0) ? 0 : OFFS[gd - 1];
    int end = OFFS[gd];
    float4 acc = {0.f, 0.f, 0.f, 0.f};
    for (int j = beg + g; j < end; j += 8) {
        int s = sorted[j];
        float w = ns[s];
        float4 v = loadx(x, ((size_t)s << 7) + c4);
        acc.x += v.x * w; acc.y += v.y * w; acc.z += v.z * w; acc.w += v.w * w;
    }
    part[g][q] = acc;
    __syncthreads();
    if (g == 0) {
        float4 a = part[0][q];
        #pragma unroll
        for (int gg = 1; gg < 8; ++gg) {
            float4 b = part[gg][q];
            a.x += b.x; a.y += b.y; a.z += b.z; a.w += b.w;
        }
        float sc = nd[row];
        ushort4 o;
        o.x = f2bf(a.x * sc); o.y = f2bf(a.y * sc);
        o.z = f2bf(a.z * sc); o.w = f2bf(a.w * sc);
        *(ushort4*)(m + ((size_t)row << 7) + c4) = o;
    }
}

// separate GEMM (small-n_dst path): 4 waves, each owns an independent 32-row tile
__global__ __launch_bounds__(256) void k_gemm_mfma(
    const ushort* __restrict__ mb, const ushort* __restrict__ Wf,
    int n, float* __restrict__ outp, float* __restrict__ stats) {
    __shared__ ushort Wl[16384];
    __shared__ float Sl[256];
    int t = threadIdx.x;
    int w = t >> 6, lane = t & 63, lm = lane & 15, lg = lane >> 4;
    Sl[t] = 0.0f;

    #pragma unroll
    for (int i = 0; i < 8; ++i) {
        int ci = t + 256 * i;
        *(short8*)&Wl[ci * 8] = *(const short8*)&Wf[ci * 8];
    }
    __syncthreads();

    int R = (blockIdx.x * 4 + w) * 32;
    float rs1[8] = {0.f, 0.f, 0.f, 0.f, 0.f, 0.f, 0.f, 0.f};
    float rs2[8] = {0.f, 0.f, 0.f, 0.f, 0.f, 0.f, 0.f, 0.f};

    if (R < n) {
        f32x4 acc[2][8] = {};
        int r0 = R + lm, r1 = R + 16 + lm;
        const ushort* a0p = mb + (((size_t)r0) << 7) + lg * 8;
        const ushort* a1p = mb + (((size_t)r1) << 7) + lg * 8;
        bool v0 = r0 < n, v1 = r1 < n;
        #pragma unroll
        for (int kbi = 0; kbi < 4; ++kbi) {
            short8 a0 = {}, a1 = {};
            if (v0) a0 = *(const short8*)(a0p + kbi * 32);
            if (v1) a1 = *(const short8*)(a1p + kbi * 32);
            #pragma unroll
            for (int c = 0; c < 8; ++c) {
                short8 b = *(short8*)&Wl[((c * 4 + kbi) * 64 + lane) * 8];
                acc[0][c] = __builtin_amdgcn_mfma_f32_16x16x32_bf16(a0, b, acc[0][c], 0, 0, 0);
                acc[1][c] = __builtin_amdgcn_mfma_f32_16x16x32_bf16(a1, b, acc[1][c], 0, 0, 0);
            }
        }
        #pragma unroll
        for (int m = 0; m < 2; ++m) {
            int rowb = R + m * 16 + lg * 4;
            #pragma unroll
            for (int c = 0; c < 8; ++c) {
                f32x4 v = acc[m][c];
                rs1[c] += v[0] + v[1] + v[2] + v[3];
                rs2[c] += v[0] * v[0] + v[1] * v[1] + v[2] * v[2] + v[3] * v[3];
                #pragma unroll
                for (int i2 = 0; i2 < 4; ++i2) {
                    int row = rowb + i2;
                    if (row < n)
                        outp[((size_t)row << 7) + c * 16 + lm] = v[i2];
                }
            }
        }
    }

    #pragma unroll
    for (int c = 0; c < 8; ++c) {
        float s1 = rs1[c], s2 = rs2[c];
        s1 += __shfl_xor(s1, 16); s1 += __shfl_xor(s1, 32);
        s2 += __shfl_xor(s2, 16); s2 += __shfl_xor(s2, 32);
        if (lg == 0) {
            atomicAdd(&Sl[c * 16 + lm], s1);
            atomicAdd(&Sl[128 + c * 16 + lm], s2);
        }
    }
    __syncthreads();
    atomicAdd(&stats[t], Sl[t]);
}

// ---------------------------------------------------------------- fused gather + MFMA (big-n_dst path)

// 512 threads = 8 waves per block, 128 rows/block. Each wave owns 16
// independent rows; lane (lm,lg) gathers row R+lm, channel octets
// (kbi*4+lg)*8 (kbi=0..3) -- exactly its MFMA A-fragment slots, accumulated
// in registers and converted to bf16 in-register. LDS holds only W (32 KB):
// 4 blocks/CU x 8 waves = 32 waves/CU (full wave cap).
template <typename XT>
__global__ __launch_bounds__(512) void k_fused2(
    const XT* __restrict__ x, const float* __restrict__ ns,
    const float* __restrict__ nd,
    const int* __restrict__ OFFS, int gdbase,
    const int* __restrict__ sorted,
    const ushort* __restrict__ Wf,
    int n, float* __restrict__ outp, float* __restrict__ stats) {
    __shared__ ushort Wl[16384];
    __shared__ float Sl[256];
    int t = threadIdx.x;
    if (t < 256) Sl[t] = 0.0f;

    #pragma unroll
    for (int i = 0; i < 4; ++i) {
        int ci = t + 512 * i;
        *(short8*)&Wl[ci * 8] = *(const short8*)&Wf[ci * 8];
    }

    int w = t >> 6, lane = t & 63, lm = lane & 15, lg = lane >> 4;
    int R = blockIdx.x * 128 + w * 16;
    int row = R + lm;

    float a[4][8] = {};
    float scale = 0.0f;
    if (row < n) {
        int gd = gdbase + row;
        int beg = (gd == 0) ? 0 : OFFS[gd - 1];
        int end = OFFS[gd];
        for (int j = beg; j < end; ++j) {
            int s = sorted[j];
            float wgt = ns[s];
            size_t xb = (size_t)s << 7;
            #pragma unroll
            for (int kbi = 0; kbi < 4; ++kbi) {
                int cb = (kbi * 4 + lg) * 8;
                float4 u0 = loadx(x, xb + cb);
                float4 u1 = loadx(x, xb + cb + 4);
                a[kbi][0] += u0.x * wgt; a[kbi][1] += u0.y * wgt;
                a[kbi][2] += u0.z * wgt; a[kbi][3] += u0.w * wgt;
                a[kbi][4] += u1.x * wgt; a[kbi][5] += u1.y * wgt;
                a[kbi][6] += u1.z * wgt; a[kbi][7] += u1.w * wgt;
            }
        }
        scale = nd[row];
    }

    // convert to bf16 A-fragments in-register
    short8 af[4];
    #pragma unroll
    for (int kbi = 0; kbi < 4; ++kbi) {
        #pragma unroll
        for (int e = 0; e < 8; ++e)
            af[kbi][e] = (short)f2bf(a[kbi][e] * scale);
    }

    __syncthreads();   // Wl ready

    float rs1[8] = {0.f, 0.f, 0.f, 0.f, 0.f, 0.f, 0.f, 0.f};
    float rs2[8] = {0.f, 0.f, 0.f, 0.f, 0.f, 0.f, 0.f, 0.f};

    if (R < n) {
        f32x4 acc[8] = {};
        #pragma unroll
        for (int kbi = 0; kbi < 4; ++kbi) {
            #pragma unroll
            for (int c = 0; c < 8; ++c) {
                short8 b = *(short8*)&Wl[((c * 4 + kbi) * 64 + lane) * 8];
                acc[c] = __builtin_amdgcn_mfma_f32_16x16x32_bf16(af[kbi], b, acc[c], 0, 0, 0);
            }
        }
        int rowb = R + lg * 4;
        #pragma unroll
        for (int c = 0; c < 8; ++c) {
            f32x4 v = acc[c];
            rs1[c] += v[0] + v[1] + v[2] + v[3];
            rs2[c] += v[0] * v[0] + v[1] * v[1] + v[2] * v[2] + v[3] * v[3];
            #pragma unroll
            for (int i2 = 0; i2 < 4; ++i2) {
                int crow = rowb + i2;
                if (crow < n)
                    outp[((size_t)crow << 7) + c * 16 + lm] = v[i2];
            }
        }
    }

    #pragma unroll
    for (int c = 0; c < 8; ++c) {
        float s1 = rs1[c], s2 = rs2[c];
        s1 += __shfl_xor(s1, 16); s1 += __shfl_xor(s1, 32);
        s2 += __shfl_xor(s2, 16); s2 += __shfl_xor(s2, 32);
        if (lg == 0) {
            atomicAdd(&Sl[c * 16 + lm], s1);
            atomicAdd(&Sl[128 + c * 16 + lm], s2);
        }
    }
    __syncthreads();
    if (t < 256) atomicAdd(&stats[t], Sl[t]);
}

// ---------------------------------------------------------------- combined 3-relation BN normalize

// l0: dst = bf16( aff0(o0) + aff1(o1) + aff2(o2) )
__global__ void k_norm3_bf(const float4* __restrict__ o0, const float4* __restrict__ o1,
                           const float4* __restrict__ o2,
                           const float* __restrict__ st0, const float* __restrict__ st1,
                           const float* __restrict__ st2,
                           const float* __restrict__ g0, const float* __restrict__ g1,
                           const float* __restrict__ g2,
                           const float* __restrict__ b0, const float* __restrict__ b1,
                           const float* __restrict__ b2,
                           float inv_n, int total4, ushort* __restrict__ dst) {
    __shared__ float sc[3][128], sh[3][128];
    int t = threadIdx.x;
    if (t < 128) {
        float mu0 = st0[t] * inv_n, va0 = st0[128 + t] * inv_n - mu0 * mu0;
        float s0 = g0[t] * rsqrtf(va0 + 1e-5f); sc[0][t] = s0; sh[0][t] = b0[t] - mu0 * s0;
        float mu1 = st1[t] * inv_n, va1 = st1[128 + t] * inv_n - mu1 * mu1;
        float s1 = g1[t] * rsqrtf(va1 + 1e-5f); sc[1][t] = s1; sh[1][t] = b1[t] - mu1 * s1;
        float mu2 = st2[t] * inv_n, va2 = st2[128 + t] * inv_n - mu2 * mu2;
        float s2 = g2[t] * rsqrtf(va2 + 1e-5f); sc[2][t] = s2; sh[2][t] = b2[t] - mu2 * s2;
    }
    __syncthreads();
    for (int i = blockIdx.x * blockDim.x + t; i < total4; i += gridDim.x * blockDim.x) {
        int c4 = (i & 31) * 4;
        float4 v0 = o0[i], v1 = o1[i], v2 = o2[i];
        float4 r;
        r.x = (v0.x * sc[0][c4+0] + sh[0][c4+0]) + (v1.x * sc[1][c4+0] + sh[1][c4+0]) + (v2.x * sc[2][c4+0] + sh[2][c4+0]);
        r.y = (v0.y * sc[0][c4+1] + sh[0][c4+1]) + (v1.y * sc[1][c4+1] + sh[1][c4+1]) + (v2.y * sc[2][c4+1] + sh[2][c4+1]);
        r.z = (v0.z * sc[0][c4+2] + sh[0][c4+2]) + (v1.z * sc[1][c4+2] + sh[1][c4+2]) + (v2.z * sc[2][c4+2] + sh[2][c4+2]);
        r.w = (v0.w * sc[0][c4+3] + sh[0][c4+3]) + (v1.w * sc[1][c4+3] + sh[1][c4+3]) + (v2.w * sc[2][c4+3] + sh[2][c4+3]);
        ushort4 o;
        o.x = f2bf(r.x); o.y = f2bf(r.y); o.z = f2bf(r.z); o.w = f2bf(r.w);
        *(ushort4*)(dst + (size_t)i * 4) = o;
    }
}

// l1: dst = aff0(o0) + aff1(o1) + aff2(o2) + resid  (fp32)
__global__ void k_norm3_f32(const float4* __restrict__ o0, const float4* __restrict__ o1,
                            const float4* __restrict__ o2,
                            const float* __restrict__ st0, const float* __restrict__ st1,
                            const float* __restrict__ st2,
                            const float* __restrict__ g0, const float* __restrict__ g1,
                            const float* __restrict__ g2,
                            const float* __restrict__ b0, const float* __restrict__ b1,
                            const float* __restrict__ b2,
                            float inv_n, int total4, float4* __restrict__ dst,
                            const float4* __restrict__ resid4) {
    __shared__ float sc[3][128], sh[3][128];
    int t = threadIdx.x;
    if (t < 128) {
        float mu0 = st0[t] * inv_n, va0 = st0[128 + t] * inv_n - mu0 * mu0;
        float s0 = g0[t] * rsqrtf(va0 + 1e-5f); sc[0][t] = s0; sh[0][t] = b0[t] - mu0 * s0;
        float mu1 = st1[t] * inv_n, va1 = st1[128 + t] * inv_n - mu1 * mu1;
        float s1 = g1[t] * rsqrtf(va1 + 1e-5f); sc[1][t] = s1; sh[1][t] = b1[t] - mu1 * s1;
        float mu2 = st2[t] * inv_n, va2 = st2[128 + t] * inv_n - mu2 * mu2;
        float s2 = g2[t] * rsqrtf(va2 + 1e-5f); sc[2][t] = s2; sh[2][t] = b2[t] - mu2 * s2;
    }
    __syncthreads();
    for (int i = blockIdx.x * blockDim.x + t; i < total4; i += gridDim.x * blockDim.x) {
        int c4 = (i & 31) * 4;
        float4 v0 = o0[i], v1 = o1[i], v2 = o2[i], d = resid4[i];
        float4 r;
        r.x = (v0.x * sc[0][c4+0] + sh[0][c4+0]) + (v1.x * sc[1][c4+0] + sh[1][c4+0]) + (v2.x * sc[2][c4+0] + sh[2][c4+0]) + d.x;
        r.y = (v0.y * sc[0][c4+1] + sh[0][c4+1]) + (v1.y * sc[1][c4+1] + sh[1][c4+1]) + (v2.y * sc[2][c4+1] + sh[2][c4+1]) + d.y;
        r.z = (v0.z * sc[0][c4+2] + sh[0][c4+2]) + (v1.z * sc[1][c4+2] + sh[1][c4+2]) + (v2.z * sc[2][c4+2] + sh[2][c4+2]) + d.z;
        r.w = (v0.w * sc[0][c4+3] + sh[0][c4+3]) + (v1.w * sc[1][c4+3] + sh[1][c4+3]) + (v2.w * sc[2][c4+3] + sh[2][c4+3]) + d.w;
        dst[i] = r;
    }
}

// ---------------------------------------------------------------- launch

extern "C" void kernel_launch(void* const* d_in, const int* in_sizes, int n_in,
                              void* d_out, int out_size, void* d_ws, size_t ws_size,
                              hipStream_t stream) {
    static const int NT[3]   = {100000, 150000, 2000};
    static const int RE[9]   = {300000, 300000, 100000, 100000, 150000, 150000, 100000, 150000, 2000};
    static const int RSRC[9] = {0, 1, 0, 2, 1, 2, 0, 1, 2};
    static const int RDST[9] = {1, 0, 2, 0, 2, 1, 0, 1, 2};
    // relations per dst type, ascending r (matches reference accumulation order)
    static const int DREL[3][3] = {{1, 3, 6}, {0, 5, 7}, {2, 4, 8}};
    const int TOT_N = 756000;
    const int NB = (TOT_N + 255) / 256;

    const float* feat_in[3] = {(const float*)d_in[0], (const float*)d_in[1], (const float*)d_in[2]};
    const float* W     = (const float*)d_in[3];
    const float* gamma = (const float*)d_in[5];
    const float* beta  = (const float*)d_in[6];
    float* ws  = (float*)d_ws;
    float* out = (float*)d_out;

    int ns_base[9], nd_base[9];
    {
        int s = 0, d = 0;
        for (int r = 0; r < 9; ++r) {
            ns_base[r] = s; s += NT[RSRC[r]];
            nd_base[r] = d; d += NT[RDST[r]];
        }
    }

    // workspace layout (float units; bf16 buffers use half-count)
    const size_t H_A    = 0;                        // 100000*128 bf16
    const size_t H_B    = H_A + 6400000;            // 150000*128 bf16
    const size_t H_G    = H_B + 9600000;            // 2000*128 bf16
    const size_t MBUF   = H_G + 128000;             // small-path m buffer (bf16)
    const size_t OUT    = MBUF + 9600000;           // 3 slots x 150000*128 fp32
    const size_t WT     = OUT + 3 * 19200000;       // 18*128*128 bf16
    const size_t STATS  = WT + 147456;              // 18*256 fp32
    const size_t NS     = STATS + 4608;             // 756000
    const size_t ND     = NS + 756000;              // 756000
    const size_t OFFS   = ND + 756000;              // 756000 ints
    const size_t SORTED = OFFS + 756000;            // 1352000 ints
    const size_t BSUM   = SORTED + 1352000;         // scan blocks

    ushort* h_feat[3] = {(ushort*)(ws + H_A), (ushort*)(ws + H_B), (ushort*)(ws + H_G)};
    float* out_feat[3] = {out, out + 12800000, out + 32000000};
    ushort* mbuf   = (ushort*)(ws + MBUF);
    float*  obuf[3] = {ws + OUT, ws + OUT + 19200000, ws + OUT + 38400000};
    ushort* wt     = (ushort*)(ws + WT);
    float*  stats0 = ws + STATS;
    float*  ns_blk = ws + NS;
    float*  nd_blk = ws + ND;
    int*    offs   = (int*)(ws + OFFS);
    int*    sorted = (int*)(ws + SORTED);
    int*    bsum   = (int*)(ws + BSUM);

    // zero stats + degree counters (contiguous)
    hipMemsetAsync(ws + STATS, 0, (4608 + 2 * 756000) * sizeof(float), stream);

    for (int r = 0; r < 9; ++r) {
        const int* src = (const int*)d_in[7 + 2 * r];
        const int* dst = (const int*)d_in[8 + 2 * r];
        k_count<<<(RE[r] + 255) / 256, 256, 0, stream>>>(
            src, dst, RE[r], ns_blk + ns_base[r], nd_blk + nd_base[r]);
    }
    k_scan1<<<NB, 256, 0, stream>>>(nd_blk, offs, bsum, TOT_N);
    k_scan2<<<1, 1024, 0, stream>>>(bsum, NB);
    k_scan3<<<NB, 256, 0, stream>>>(offs, bsum, TOT_N);
    for (int r = 0; r < 9; ++r) {
        const int* src = (const int*)d_in[7 + 2 * r];
        const int* dst = (const int*)d_in[8 + 2 * r];
        k_fill<<<(RE[r] + 255) / 256, 256, 0, stream>>>(
            src, dst, RE[r], offs + nd_base[r], sorted);
    }
    k_rsqrt<<<(2 * TOT_N + 255) / 256, 256, 0, stream>>>(ns_blk, 2 * TOT_N);
    k_prepw<<<(18 * 16384 + 255) / 256, 256, 0, stream>>>(W, wt);

    for (int l = 0; l < 2; ++l) {
        for (int dt = 0; dt < 3; ++dt) {
            int n_dst = NT[dt];
            const int* rl = DREL[dt];

            for (int s = 0; s < 3; ++s) {
                int r = rl[s];
                int st = RSRC[r];
                float* stats = stats0 + (size_t)(l * 9 + r) * 256;
                const ushort* wfr = wt + (size_t)(l * 9 + r) * 16384;

                if (dt == 2) {
                    // small-n_dst, high-degree path: block-per-row gather + separate GEMM
                    if (l == 0)
                        k_gather_row<float><<<n_dst, 256, 0, stream>>>(
                            feat_in[st], ns_blk + ns_base[r], nd_blk + nd_base[r],
                            offs, nd_base[r], sorted, n_dst, mbuf);
                    else
                        k_gather_row<ushort><<<n_dst, 256, 0, stream>>>(
                            h_feat[st], ns_blk + ns_base[r], nd_blk + nd_base[r],
                            offs, nd_base[r], sorted, n_dst, mbuf);
                    k_gemm_mfma<<<(n_dst + 127) / 128, 256, 0, stream>>>(
                        mbuf, wfr, n_dst, obuf[s], stats);
                } else {
                    int nblk = (n_dst + 127) / 128;
                    if (l == 0)
                        k_fused2<float><<<nblk, 512, 0, stream>>>(
                            feat_in[st], ns_blk + ns_base[r], nd_blk + nd_base[r],
                            offs, nd_base[r], sorted, wfr, n_dst, obuf[s], stats);
                    else
                        k_fused2<ushort><<<nblk, 512, 0, stream>>>(
                            h_feat[st], ns_blk + ns_base[r], nd_blk + nd_base[r],
                            offs, nd_base[r], sorted, wfr, n_dst, obuf[s], stats);
                }
            }

            // one combined norm for this dst
            int r0 = rl[0], r1 = rl[1], r2 = rl[2];
            const float* st0 = stats0 + (size_t)(l * 9 + r0) * 256;
            const float* st1 = stats0 + (size_t)(l * 9 + r1) * 256;
            const float* st2 = stats0 + (size_t)(l * 9 + r2) * 256;
            const float* g0 = gamma + (size_t)(l * 9 + r0) * D;
            const float* g1 = gamma + (size_t)(l * 9 + r1) * D;
            const float* g2 = gamma + (size_t)(l * 9 + r2) * D;
            const float* b0 = beta + (size_t)(l * 9 + r0) * D;
            const float* b1 = beta + (size_t)(l * 9 + r1) * D;
            const float* b2 = beta + (size_t)(l * 9 + r2) * D;
            int total4 = n_dst * 32;
            int ngrid = (total4 + 255) / 256;
            if (ngrid > 2048) ngrid = 2048;
            float inv_n = 1.0f / (float)n_dst;

            if (l == 0)
                k_norm3_bf<<<ngrid, 256, 0, stream>>>(
                    (const float4*)obuf[0], (const float4*)obuf[1], (const float4*)obuf[2],
                    st0, st1, st2, g0, g1, g2, b0, b1, b2,
                    inv_n, total4, h_feat[dt]);
            else
                k_norm3_f32<<<ngrid, 256, 0, stream>>>(
                    (const float4*)obuf[0], (const float4*)obuf[1], (const float4*)obuf[2],
                    st0, st1, st2, g0, g1, g2, b0, b1, b2,
                    inv_n, total4, (float4*)out_feat[dt], (const float4*)feat_in[dt]);
        }
    }
}

// Round 9
// 1256.670 us; speedup vs baseline: 2.6730x; 1.1698x over previous
//
#include <hip/hip_runtime.h>
#include <cstdint>

#define D 128

typedef __attribute__((ext_vector_type(8))) short short8;
typedef __attribute__((ext_vector_type(4))) float f32x4;

__device__ inline ushort f2bf(float f) {
    uint u = __float_as_uint(f);
    uint r = (u + 0x7fffu + ((u >> 16) & 1u)) >> 16;
    return (ushort)r;
}
__device__ inline float bf2f(ushort u) { return __uint_as_float(((uint)u) << 16); }

// ---------------------------------------------------------------- degree / CSR build

__global__ void k_count(const int* __restrict__ src, const int* __restrict__ dst,
                        int E, float* __restrict__ degs, float* __restrict__ degd) {
    int i = blockIdx.x * blockDim.x + threadIdx.x;
    if (i < E) {
        atomicAdd(&degs[src[i]], 1.0f);
        atomicAdd(&degd[dst[i]], 1.0f);
    }
}

__global__ void k_rsqrt(float* __restrict__ p, int n) {
    int i = blockIdx.x * blockDim.x + threadIdx.x;
    if (i < n) {
        float d = p[i];
        p[i] = d > 0.0f ? rsqrtf(d) : 0.0f;
    }
}

__global__ void k_scan1(const float* __restrict__ cnt, int* __restrict__ off,
                        int* __restrict__ bsum, int n) {
    __shared__ int s[256];
    int t = threadIdx.x, i = blockIdx.x * 256 + t;
    int v = (i < n) ? (int)cnt[i] : 0;
    int acc = v;
    s[t] = acc; __syncthreads();
    for (int d = 1; d < 256; d <<= 1) {
        int add = (t >= d) ? s[t - d] : 0;
        __syncthreads();
        acc += add; s[t] = acc; __syncthreads();
    }
    if (i < n) off[i] = acc - v;
    if (t == 255) bsum[blockIdx.x] = acc;
}

__global__ __launch_bounds__(1024) void k_scan2(int* __restrict__ bsum, int nb) {
    __shared__ int s[1024];
    int t = threadIdx.x;
    int i0 = t * 3;
    int v0 = (i0     < nb) ? bsum[i0]     : 0;
    int v1 = (i0 + 1 < nb) ? bsum[i0 + 1] : 0;
    int v2 = (i0 + 2 < nb) ? bsum[i0 + 2] : 0;
    int tot = v0 + v1 + v2;
    int acc = tot;
    s[t] = acc; __syncthreads();
    for (int d = 1; d < 1024; d <<= 1) {
        int add = (t >= d) ? s[t - d] : 0;
        __syncthreads();
        acc += add; s[t] = acc; __syncthreads();
    }
    int base = acc - tot;
    if (i0     < nb) bsum[i0]     = base;
    if (i0 + 1 < nb) bsum[i0 + 1] = base + v0;
    if (i0 + 2 < nb) bsum[i0 + 2] = base + v0 + v1;
}

__global__ void k_scan3(int* __restrict__ off, const int* __restrict__ bsum, int n) {
    int i = blockIdx.x * 256 + threadIdx.x;
    if (i < n) off[i] += bsum[blockIdx.x];
}

__global__ void k_fill(const int* __restrict__ src, const int* __restrict__ dst,
                       int E, int* __restrict__ offs, int* __restrict__ sorted) {
    int e = blockIdx.x * blockDim.x + threadIdx.x;
    if (e < E) {
        int pos = atomicAdd(&offs[dst[e]], 1);
        sorted[pos] = src[e];
    }
}

// W[18][128k][128n] fp32 -> Wf fragment-major bf16:
// Wf[r][c][kbi][lane][e]  (c=col-tile 0..7, kbi=k-block 0..3, lane=lm+16*lg, e=0..7)
//   holds W[k = kbi*32 + lg*8 + e][ncol = c*16 + lm]
__global__ void k_prepw(const float* __restrict__ W, ushort* __restrict__ Wf) {
    int i = blockIdx.x * 256 + threadIdx.x;
    if (i < 18 * 16384) {
        int r = i >> 14, j = i & 16383;
        int e = j & 7, lane = (j >> 3) & 63, kbi = (j >> 9) & 3, c = j >> 11;
        int lm = lane & 15, lg = lane >> 4;
        int k = kbi * 32 + lg * 8 + e, ncol = c * 16 + lm;
        Wf[i] = f2bf(W[(r << 14) + (k << 7) + ncol]);
    }
}

// ---------------------------------------------------------------- gather helpers

__device__ inline float4 loadx(const float* x, size_t idx) { return *(const float4*)(x + idx); }
__device__ inline float4 loadx(const ushort* x, size_t idx) {
    ushort4 u = *(const ushort4*)(x + idx);
    float4 v;
    v.x = bf2f(u.x); v.y = bf2f(u.y); v.z = bf2f(u.z); v.w = bf2f(u.w);
    return v;
}

// small-n_dst, high-degree path: ONE BLOCK PER ROW.
// 8 edge-groups x 32 channel-quads; each thread strides the edge list by 8
// with next-index prefetch; partials reduced through LDS.
template <typename XT>
__global__ __launch_bounds__(256) void k_gather_row(
    const XT* __restrict__ x, const float* __restrict__ ns,
    const float* __restrict__ nd,
    const int* __restrict__ OFFS, int gdbase,
    const int* __restrict__ sorted, int n_dst,
    ushort* __restrict__ m) {
    __shared__ float4 part[8][32];
    int row = blockIdx.x;
    if (row >= n_dst) return;
    int t = threadIdx.x;
    int g = t >> 5, q = t & 31;
    int c4 = q * 4;
    int gd = gdbase + row;
    int beg = (gd == 0) ? 0 : OFFS[gd - 1];
    int end = OFFS[gd];
    float4 acc = {0.f, 0.f, 0.f, 0.f};
    int j = beg + g;
    int sN = (j < end) ? sorted[j] : 0;
    while (j < end) {
        int s = sN;
        if (j + 8 < end) sN = sorted[j + 8];   // prefetch next strided index
        float w = ns[s];
        float4 v = loadx(x, ((size_t)s << 7) + c4);
        acc.x += v.x * w; acc.y += v.y * w; acc.z += v.z * w; acc.w += v.w * w;
        j += 8;
    }
    part[g][q] = acc;
    __syncthreads();
    if (g == 0) {
        float4 a = part[0][q];
        #pragma unroll
        for (int gg = 1; gg < 8; ++gg) {
            float4 b = part[gg][q];
            a.x += b.x; a.y += b.y; a.z += b.z; a.w += b.w;
        }
        float sc = nd[row];
        ushort4 o;
        o.x = f2bf(a.x * sc); o.y = f2bf(a.y * sc);
        o.z = f2bf(a.z * sc); o.w = f2bf(a.w * sc);
        *(ushort4*)(m + ((size_t)row << 7) + c4) = o;
    }
}

// separate GEMM (small-n_dst path): 4 waves, each owns an independent 32-row tile
__global__ __launch_bounds__(256) void k_gemm_mfma(
    const ushort* __restrict__ mb, const ushort* __restrict__ Wf,
    int n, float* __restrict__ outp, float* __restrict__ stats) {
    __shared__ ushort Wl[16384];
    __shared__ float Sl[256];
    int t = threadIdx.x;
    int w = t >> 6, lane = t & 63, lm = lane & 15, lg = lane >> 4;
    Sl[t] = 0.0f;

    #pragma unroll
    for (int i = 0; i < 8; ++i) {
        int ci = t + 256 * i;
        *(short8*)&Wl[ci * 8] = *(const short8*)&Wf[ci * 8];
    }
    __syncthreads();

    int R = (blockIdx.x * 4 + w) * 32;
    float rs1[8] = {0.f, 0.f, 0.f, 0.f, 0.f, 0.f, 0.f, 0.f};
    float rs2[8] = {0.f, 0.f, 0.f, 0.f, 0.f, 0.f, 0.f, 0.f};

    if (R < n) {
        f32x4 acc[2][8] = {};
        int r0 = R + lm, r1 = R + 16 + lm;
        const ushort* a0p = mb + (((size_t)r0) << 7) + lg * 8;
        const ushort* a1p = mb + (((size_t)r1) << 7) + lg * 8;
        bool v0 = r0 < n, v1 = r1 < n;
        #pragma unroll
        for (int kbi = 0; kbi < 4; ++kbi) {
            short8 a0 = {}, a1 = {};
            if (v0) a0 = *(const short8*)(a0p + kbi * 32);
            if (v1) a1 = *(const short8*)(a1p + kbi * 32);
            #pragma unroll
            for (int c = 0; c < 8; ++c) {
                short8 b = *(short8*)&Wl[((c * 4 + kbi) * 64 + lane) * 8];
                acc[0][c] = __builtin_amdgcn_mfma_f32_16x16x32_bf16(a0, b, acc[0][c], 0, 0, 0);
                acc[1][c] = __builtin_amdgcn_mfma_f32_16x16x32_bf16(a1, b, acc[1][c], 0, 0, 0);
            }
        }
        #pragma unroll
        for (int m = 0; m < 2; ++m) {
            int rowb = R + m * 16 + lg * 4;
            #pragma unroll
            for (int c = 0; c < 8; ++c) {
                f32x4 v = acc[m][c];
                rs1[c] += v[0] + v[1] + v[2] + v[3];
                rs2[c] += v[0] * v[0] + v[1] * v[1] + v[2] * v[2] + v[3] * v[3];
                #pragma unroll
                for (int i2 = 0; i2 < 4; ++i2) {
                    int row = rowb + i2;
                    if (row < n)
                        outp[((size_t)row << 7) + c * 16 + lm] = v[i2];
                }
            }
        }
    }

    #pragma unroll
    for (int c = 0; c < 8; ++c) {
        float s1 = rs1[c], s2 = rs2[c];
        s1 += __shfl_xor(s1, 16); s1 += __shfl_xor(s1, 32);
        s2 += __shfl_xor(s2, 16); s2 += __shfl_xor(s2, 32);
        if (lg == 0) {
            atomicAdd(&Sl[c * 16 + lm], s1);
            atomicAdd(&Sl[128 + c * 16 + lm], s2);
        }
    }
    __syncthreads();
    atomicAdd(&stats[t], Sl[t]);
}

// ---------------------------------------------------------------- merged fused gather + MFMA (big-n_dst path)

// One launch covers the THREE relations of a (layer, dst-type) group:
// grid = 3*nblk, rel = blockIdx.x % 3 (interleaved so relations backfill each
// other's drain). Per block: 512 thr = 8 waves, 128 rows. Lane (lm,lg)
// gathers row R+lm's channel octets (kbi*4+lg)*8 with next-edge index
// prefetch, accumulates in registers, converts to bf16 A-fragments
// in-register, MFMAs against the relation's W (32 KB LDS, conflict-free).
struct FatArgs {
    const void*  x[3];
    const float* ns[3];
    const float* nd[3];
    const ushort* wf[3];
    float* outp[3];
    float* stats[3];
    int gdbase[3];
};

template <typename XT>
__global__ __launch_bounds__(512) void k_fused3(
    FatArgs fa, const int* __restrict__ OFFS, const int* __restrict__ sorted,
    int n) {
    __shared__ ushort Wl[16384];
    __shared__ float Sl[256];
    int rel  = blockIdx.x % 3;
    int tile = blockIdx.x / 3;
    const XT*    x     = (const XT*)fa.x[rel];
    const float* ns    = fa.ns[rel];
    const float* nd    = fa.nd[rel];
    const ushort* Wf   = fa.wf[rel];
    float* outp        = fa.outp[rel];
    float* stats       = fa.stats[rel];
    int gdbase         = fa.gdbase[rel];

    int t = threadIdx.x;
    if (t < 256) Sl[t] = 0.0f;

    #pragma unroll
    for (int i = 0; i < 4; ++i) {
        int ci = t + 512 * i;
        *(short8*)&Wl[ci * 8] = *(const short8*)&Wf[ci * 8];
    }

    int w = t >> 6, lane = t & 63, lm = lane & 15, lg = lane >> 4;
    int R = tile * 128 + w * 16;
    int row = R + lm;

    float a[4][8] = {};
    float scale = 0.0f;
    if (row < n) {
        int gd = gdbase + row;
        int beg = (gd == 0) ? 0 : OFFS[gd - 1];
        int end = OFFS[gd];
        int j = beg;
        int sN = (j < end) ? sorted[j] : 0;
        while (j < end) {
            int s = sN;
            if (j + 1 < end) sN = sorted[j + 1];   // prefetch next index
            float wgt = ns[s];
            size_t xb = (size_t)s << 7;
            #pragma unroll
            for (int kbi = 0; kbi < 4; ++kbi) {
                int cb = (kbi * 4 + lg) * 8;
                float4 u0 = loadx(x, xb + cb);
                float4 u1 = loadx(x, xb + cb + 4);
                a[kbi][0] += u0.x * wgt; a[kbi][1] += u0.y * wgt;
                a[kbi][2] += u0.z * wgt; a[kbi][3] += u0.w * wgt;
                a[kbi][4] += u1.x * wgt; a[kbi][5] += u1.y * wgt;
                a[kbi][6] += u1.z * wgt; a[kbi][7] += u1.w * wgt;
            }
            ++j;
        }
        scale = nd[row];
    }

    // convert to bf16 A-fragments in-register
    short8 af[4];
    #pragma unroll
    for (int kbi = 0; kbi < 4; ++kbi) {
        #pragma unroll
        for (int e = 0; e < 8; ++e)
            af[kbi][e] = (short)f2bf(a[kbi][e] * scale);
    }

    __syncthreads();   // Wl ready

    float rs1[8] = {0.f, 0.f, 0.f, 0.f, 0.f, 0.f, 0.f, 0.f};
    float rs2[8] = {0.f, 0.f, 0.f, 0.f, 0.f, 0.f, 0.f, 0.f};

    if (R < n) {
        f32x4 acc[8] = {};
        #pragma unroll
        for (int kbi = 0; kbi < 4; ++kbi) {
            #pragma unroll
            for (int c = 0; c < 8; ++c) {
                short8 b = *(short8*)&Wl[((c * 4 + kbi) * 64 + lane) * 8];
                acc[c] = __builtin_amdgcn_mfma_f32_16x16x32_bf16(af[kbi], b, acc[c], 0, 0, 0);
            }
        }
        int rowb = R + lg * 4;
        #pragma unroll
        for (int c = 0; c < 8; ++c) {
            f32x4 v = acc[c];
            rs1[c] += v[0] + v[1] + v[2] + v[3];
            rs2[c] += v[0] * v[0] + v[1] * v[1] + v[2] * v[2] + v[3] * v[3];
            #pragma unroll
            for (int i2 = 0; i2 < 4; ++i2) {
                int crow = rowb + i2;
                if (crow < n)
                    outp[((size_t)crow << 7) + c * 16 + lm] = v[i2];
            }
        }
    }

    #pragma unroll
    for (int c = 0; c < 8; ++c) {
        float s1 = rs1[c], s2 = rs2[c];
        s1 += __shfl_xor(s1, 16); s1 += __shfl_xor(s1, 32);
        s2 += __shfl_xor(s2, 16); s2 += __shfl_xor(s2, 32);
        if (lg == 0) {
            atomicAdd(&Sl[c * 16 + lm], s1);
            atomicAdd(&Sl[128 + c * 16 + lm], s2);
        }
    }
    __syncthreads();
    if (t < 256) atomicAdd(&stats[t], Sl[t]);
}

// ---------------------------------------------------------------- combined 3-relation BN normalize

// l0: dst = bf16( aff0(o0) + aff1(o1) + aff2(o2) )
__global__ void k_norm3_bf(const float4* __restrict__ o0, const float4* __restrict__ o1,
                           const float4* __restrict__ o2,
                           const float* __restrict__ st0, const float* __restrict__ st1,
                           const float* __restrict__ st2,
                           const float* __restrict__ g0, const float* __restrict__ g1,
                           const float* __restrict__ g2,
                           const float* __restrict__ b0, const float* __restrict__ b1,
                           const float* __restrict__ b2,
                           float inv_n, int total4, ushort* __restrict__ dst) {
    __shared__ float sc[3][128], sh[3][128];
    int t = threadIdx.x;
    if (t < 128) {
        float mu0 = st0[t] * inv_n, va0 = st0[128 + t] * inv_n - mu0 * mu0;
        float s0 = g0[t] * rsqrtf(va0 + 1e-5f); sc[0][t] = s0; sh[0][t] = b0[t] - mu0 * s0;
        float mu1 = st1[t] * inv_n, va1 = st1[128 + t] * inv_n - mu1 * mu1;
        float s1 = g1[t] * rsqrtf(va1 + 1e-5f); sc[1][t] = s1; sh[1][t] = b1[t] - mu1 * s1;
        float mu2 = st2[t] * inv_n, va2 = st2[128 + t] * inv_n - mu2 * mu2;
        float s2 = g2[t] * rsqrtf(va2 + 1e-5f); sc[2][t] = s2; sh[2][t] = b2[t] - mu2 * s2;
    }
    __syncthreads();
    for (int i = blockIdx.x * blockDim.x + t; i < total4; i += gridDim.x * blockDim.x) {
        int c4 = (i & 31) * 4;
        float4 v0 = o0[i], v1 = o1[i], v2 = o2[i];
        float4 r;
        r.x = (v0.x * sc[0][c4+0] + sh[0][c4+0]) + (v1.x * sc[1][c4+0] + sh[1][c4+0]) + (v2.x * sc[2][c4+0] + sh[2][c4+0]);
        r.y = (v0.y * sc[0][c4+1] + sh[0][c4+1]) + (v1.y * sc[1][c4+1] + sh[1][c4+1]) + (v2.y * sc[2][c4+1] + sh[2][c4+1]);
        r.z = (v0.z * sc[0][c4+2] + sh[0][c4+2]) + (v1.z * sc[1][c4+2] + sh[1][c4+2]) + (v2.z * sc[2][c4+2] + sh[2][c4+2]);
        r.w = (v0.w * sc[0][c4+3] + sh[0][c4+3]) + (v1.w * sc[1][c4+3] + sh[1][c4+3]) + (v2.w * sc[2][c4+3] + sh[2][c4+3]);
        ushort4 o;
        o.x = f2bf(r.x); o.y = f2bf(r.y); o.z = f2bf(r.z); o.w = f2bf(r.w);
        *(ushort4*)(dst + (size_t)i * 4) = o;
    }
}

// l1: dst = aff0(o0) + aff1(o1) + aff2(o2) + resid  (fp32)
__global__ void k_norm3_f32(const float4* __restrict__ o0, const float4* __restrict__ o1,
                            const float4* __restrict__ o2,
                            const float* __restrict__ st0, const float* __restrict__ st1,
                            const float* __restrict__ st2,
                            const float* __restrict__ g0, const float* __restrict__ g1,
                            const float* __restrict__ g2,
                            const float* __restrict__ b0, const float* __restrict__ b1,
                            const float* __restrict__ b2,
                            float inv_n, int total4, float4* __restrict__ dst,
                            const float4* __restrict__ resid4) {
    __shared__ float sc[3][128], sh[3][128];
    int t = threadIdx.x;
    if (t < 128) {
        float mu0 = st0[t] * inv_n, va0 = st0[128 + t] * inv_n - mu0 * mu0;
        float s0 = g0[t] * rsqrtf(va0 + 1e-5f); sc[0][t] = s0; sh[0][t] = b0[t] - mu0 * s0;
        float mu1 = st1[t] * inv_n, va1 = st1[128 + t] * inv_n - mu1 * mu1;
        float s1 = g1[t] * rsqrtf(va1 + 1e-5f); sc[1][t] = s1; sh[1][t] = b1[t] - mu1 * s1;
        float mu2 = st2[t] * inv_n, va2 = st2[128 + t] * inv_n - mu2 * mu2;
        float s2 = g2[t] * rsqrtf(va2 + 1e-5f); sc[2][t] = s2; sh[2][t] = b2[t] - mu2 * s2;
    }
    __syncthreads();
    for (int i = blockIdx.x * blockDim.x + t; i < total4; i += gridDim.x * blockDim.x) {
        int c4 = (i & 31) * 4;
        float4 v0 = o0[i], v1 = o1[i], v2 = o2[i], d = resid4[i];
        float4 r;
        r.x = (v0.x * sc[0][c4+0] + sh[0][c4+0]) + (v1.x * sc[1][c4+0] + sh[1][c4+0]) + (v2.x * sc[2][c4+0] + sh[2][c4+0]) + d.x;
        r.y = (v0.y * sc[0][c4+1] + sh[0][c4+1]) + (v1.y * sc[1][c4+1] + sh[1][c4+1]) + (v2.y * sc[2][c4+1] + sh[2][c4+1]) + d.y;
        r.z = (v0.z * sc[0][c4+2] + sh[0][c4+2]) + (v1.z * sc[1][c4+2] + sh[1][c4+2]) + (v2.z * sc[2][c4+2] + sh[2][c4+2]) + d.z;
        r.w = (v0.w * sc[0][c4+3] + sh[0][c4+3]) + (v1.w * sc[1][c4+3] + sh[1][c4+3]) + (v2.w * sc[2][c4+3] + sh[2][c4+3]) + d.w;
        dst[i] = r;
    }
}

// ---------------------------------------------------------------- launch

extern "C" void kernel_launch(void* const* d_in, const int* in_sizes, int n_in,
                              void* d_out, int out_size, void* d_ws, size_t ws_size,
                              hipStream_t stream) {
    static const int NT[3]   = {100000, 150000, 2000};
    static const int RE[9]   = {300000, 300000, 100000, 100000, 150000, 150000, 100000, 150000, 2000};
    static const int RSRC[9] = {0, 1, 0, 2, 1, 2, 0, 1, 2};
    static const int RDST[9] = {1, 0, 2, 0, 2, 1, 0, 1, 2};
    // relations per dst type, ascending r (matches reference accumulation order)
    static const int DREL[3][3] = {{1, 3, 6}, {0, 5, 7}, {2, 4, 8}};
    const int TOT_N = 756000;
    const int NB = (TOT_N + 255) / 256;

    const float* feat_in[3] = {(const float*)d_in[0], (const float*)d_in[1], (const float*)d_in[2]};
    const float* W     = (const float*)d_in[3];
    const float* gamma = (const float*)d_in[5];
    const float* beta  = (const float*)d_in[6];
    float* ws  = (float*)d_ws;
    float* out = (float*)d_out;

    int ns_base[9], nd_base[9];
    {
        int s = 0, d = 0;
        for (int r = 0; r < 9; ++r) {
            ns_base[r] = s; s += NT[RSRC[r]];
            nd_base[r] = d; d += NT[RDST[r]];
        }
    }

    // workspace layout (float units; bf16 buffers use half-count)
    const size_t H_A    = 0;                        // 100000*128 bf16
    const size_t H_B    = H_A + 6400000;            // 150000*128 bf16
    const size_t H_G    = H_B + 9600000;            // 2000*128 bf16
    const size_t MBUF   = H_G + 128000;             // small-path m buffer (bf16)
    const size_t OUT    = MBUF + 9600000;           // 3 slots x 150000*128 fp32
    const size_t WT     = OUT + 3 * 19200000;       // 18*128*128 bf16
    const size_t STATS  = WT + 147456;              // 18*256 fp32
    const size_t NS     = STATS + 4608;             // 756000
    const size_t ND     = NS + 756000;              // 756000
    const size_t OFFS   = ND + 756000;              // 756000 ints
    const size_t SORTED = OFFS + 756000;            // 1352000 ints
    const size_t BSUM   = SORTED + 1352000;         // scan blocks

    ushort* h_feat[3] = {(ushort*)(ws + H_A), (ushort*)(ws + H_B), (ushort*)(ws + H_G)};
    float* out_feat[3] = {out, out + 12800000, out + 32000000};
    ushort* mbuf   = (ushort*)(ws + MBUF);
    float*  obuf[3] = {ws + OUT, ws + OUT + 19200000, ws + OUT + 38400000};
    ushort* wt     = (ushort*)(ws + WT);
    float*  stats0 = ws + STATS;
    float*  ns_blk = ws + NS;
    float*  nd_blk = ws + ND;
    int*    offs   = (int*)(ws + OFFS);
    int*    sorted = (int*)(ws + SORTED);
    int*    bsum   = (int*)(ws + BSUM);

    // zero stats + degree counters (contiguous)
    hipMemsetAsync(ws + STATS, 0, (4608 + 2 * 756000) * sizeof(float), stream);

    for (int r = 0; r < 9; ++r) {
        const int* src = (const int*)d_in[7 + 2 * r];
        const int* dst = (const int*)d_in[8 + 2 * r];
        k_count<<<(RE[r] + 255) / 256, 256, 0, stream>>>(
            src, dst, RE[r], ns_blk + ns_base[r], nd_blk + nd_base[r]);
    }
    k_scan1<<<NB, 256, 0, stream>>>(nd_blk, offs, bsum, TOT_N);
    k_scan2<<<1, 1024, 0, stream>>>(bsum, NB);
    k_scan3<<<NB, 256, 0, stream>>>(offs, bsum, TOT_N);
    for (int r = 0; r < 9; ++r) {
        const int* src = (const int*)d_in[7 + 2 * r];
        const int* dst = (const int*)d_in[8 + 2 * r];
        k_fill<<<(RE[r] + 255) / 256, 256, 0, stream>>>(
            src, dst, RE[r], offs + nd_base[r], sorted);
    }
    k_rsqrt<<<(2 * TOT_N + 255) / 256, 256, 0, stream>>>(ns_blk, 2 * TOT_N);
    k_prepw<<<(18 * 16384 + 255) / 256, 256, 0, stream>>>(W, wt);

    for (int l = 0; l < 2; ++l) {
        for (int dt = 0; dt < 3; ++dt) {
            int n_dst = NT[dt];
            const int* rl = DREL[dt];

            if (dt == 2) {
                for (int s = 0; s < 3; ++s) {
                    int r = rl[s];
                    int st = RSRC[r];
                    float* stats = stats0 + (size_t)(l * 9 + r) * 256;
                    const ushort* wfr = wt + (size_t)(l * 9 + r) * 16384;
                    // small-n_dst, high-degree path: block-per-row gather + separate GEMM
                    if (l == 0)
                        k_gather_row<float><<<n_dst, 256, 0, stream>>>(
                            feat_in[st], ns_blk + ns_base[r], nd_blk + nd_base[r],
                            offs, nd_base[r], sorted, n_dst, mbuf);
                    else
                        k_gather_row<ushort><<<n_dst, 256, 0, stream>>>(
                            h_feat[st], ns_blk + ns_base[r], nd_blk + nd_base[r],
                            offs, nd_base[r], sorted, n_dst, mbuf);
                    k_gemm_mfma<<<(n_dst + 127) / 128, 256, 0, stream>>>(
                        mbuf, wfr, n_dst, obuf[s], stats);
                }
            } else {
                // merged big-path launch: 3 relations in one grid
                FatArgs fa;
                for (int s = 0; s < 3; ++s) {
                    int r = rl[s];
                    int st = RSRC[r];
                    fa.x[s]      = (l == 0) ? (const void*)feat_in[st] : (const void*)h_feat[st];
                    fa.ns[s]     = ns_blk + ns_base[r];
                    fa.nd[s]     = nd_blk + nd_base[r];
                    fa.wf[s]     = wt + (size_t)(l * 9 + r) * 16384;
                    fa.outp[s]   = obuf[s];
                    fa.stats[s]  = stats0 + (size_t)(l * 9 + r) * 256;
                    fa.gdbase[s] = nd_base[r];
                }
                int nblk = (n_dst + 127) / 128;
                if (l == 0)
                    k_fused3<float><<<nblk * 3, 512, 0, stream>>>(fa, offs, sorted, n_dst);
                else
                    k_fused3<ushort><<<nblk * 3, 512, 0, stream>>>(fa, offs, sorted, n_dst);
            }

            // one combined norm for this dst
            int r0 = rl[0], r1 = rl[1], r2 = rl[2];
            const float* st0 = stats0 + (size_t)(l * 9 + r0) * 256;
            const float* st1 = stats0 + (size_t)(l * 9 + r1) * 256;
            const float* st2 = stats0 + (size_t)(l * 9 + r2) * 256;
            const float* g0 = gamma + (size_t)(l * 9 + r0) * D;
            const float* g1 = gamma + (size_t)(l * 9 + r1) * D;
            const float* g2 = gamma + (size_t)(l * 9 + r2) * D;
            const float* b0 = beta + (size_t)(l * 9 + r0) * D;
            const float* b1 = beta + (size_t)(l * 9 + r1) * D;
            const float* b2 = beta + (size_t)(l * 9 + r2) * D;
            int total4 = n_dst * 32;
            int ngrid = (total4 + 255) / 256;
            if (ngrid > 2048) ngrid = 2048;
            float inv_n = 1.0f / (float)n_dst;

            if (l == 0)
                k_norm3_bf<<<ngrid, 256, 0, stream>>>(
                    (const float4*)obuf[0], (const float4*)obuf[1], (const float4*)obuf[2],
                    st0, st1, st2, g0, g1, g2, b0, b1, b2,
                    inv_n, total4, h_feat[dt]);
            else
                k_norm3_f32<<<ngrid, 256, 0, stream>>>(
                    (const float4*)obuf[0], (const float4*)obuf[1], (const float4*)obuf[2],
                    st0, st1, st2, g0, g1, g2, b0, b1, b2,
                    inv_n, total4, (float4*)out_feat[dt], (const float4*)feat_in[dt]);
        }
    }
}